// Round 7
// baseline (2525.301 us; speedup 1.0000x reference)
//
#include <hip/hip_runtime.h>

typedef __bf16 bf16_t;
typedef __attribute__((ext_vector_type(8))) __bf16 bf16x8;
typedef __attribute__((ext_vector_type(4))) float f32x4;
typedef __attribute__((ext_vector_type(16))) float f32x16;

#define NH   8
#define DH   64
#define DD   512
#define NPIX 65536   // 256*256

__device__ __forceinline__ unsigned short f2bf(float f) {
  unsigned int u = __builtin_bit_cast(unsigned int, f);
  u += 0x7fffu + ((u >> 16) & 1u);
  return (unsigned short)(u >> 16);
}
__device__ __forceinline__ float bf2f(unsigned short b) {
  return __builtin_bit_cast(float, ((unsigned int)b) << 16);
}
__device__ __forceinline__ unsigned cvtpk(float a, float b) {
  unsigned r;
  asm("v_cvt_pk_bf16_f32 %0, %1, %2" : "=v"(r) : "v"(a), "v"(b));
  return r;
}

__device__ __forceinline__ void gload_lds16(const void* g, void* l) {
  __builtin_amdgcn_global_load_lds(
      (const __attribute__((address_space(1))) void*)(uintptr_t)g,
      (__attribute__((address_space(3))) void*)(uintptr_t)l, 16, 0, 0);
}

// ---------------- elementwise fp32 -> bf16 convert (weights) ----------------
__global__ __launch_bounds__(256) void k_cvt(const float* __restrict__ in,
                                             unsigned short* __restrict__ out, int n4) {
  int i = blockIdx.x * 256 + threadIdx.x;
  if (i >= n4) return;
  float4 v = ((const float4*)in)[i];
  ushort4 o; o.x = f2bf(v.x); o.y = f2bf(v.y); o.z = f2bf(v.z); o.w = f2bf(v.w);
  ((ushort4*)out)[i] = o;
}

// ------------- x [512][65536] f32 -> x^T [65536][512] bf16 ------------------
__global__ __launch_bounds__(256) void k_cvt_transpose(const float* __restrict__ x,
                                                       unsigned short* __restrict__ xt) {
  __shared__ unsigned short Xs[64 * 68];
  int p0 = blockIdx.x * 64, c0 = blockIdx.y * 64;
  int t = threadIdx.x;
  for (int rep = 0; rep < 4; ++rep) {
    int f = rep * 256 + t, i = f >> 4, jj = f & 15;
    float4 v = *(const float4*)(x + (size_t)(c0 + i) * NPIX + p0 + jj * 4);
    ushort4 o; o.x = f2bf(v.x); o.y = f2bf(v.y); o.z = f2bf(v.z); o.w = f2bf(v.w);
    *(ushort4*)(Xs + i * 68 + jj * 4) = o;
  }
  __syncthreads();
  int j = t >> 2, q = t & 3;
  unsigned short* dst = xt + (size_t)(p0 + j) * DD + c0 + q * 16;
  for (int h2 = 0; h2 < 2; ++h2) {
    union { unsigned short u[8]; uint4 v; } pk;
    for (int cc = 0; cc < 8; ++cc) pk.u[cc] = Xs[(q * 16 + h2 * 8 + cc) * 68 + j];
    *(uint4*)(dst + h2 * 8) = pk.v;
  }
}

// ---------------- GEMM: C[1536][65536] = W[1536][512] @ X + b ---------------
// 256x256 tile, BK=64, 8 waves (2Mx4N). SINGLE-buffered 64 KiB LDS so TWO
// blocks co-reside per CU: one block's stage+vmcnt stall hides under the
// partner block's MFMA phase (m114 cross-block overlap).
// Per K-tile: barrier -> STAGE(kt) -> vmcnt(0)+barrier -> ds_reads + MFMA.
__global__ __launch_bounds__(512, 4) void k_gemm(const unsigned short* __restrict__ A,
                                                 const unsigned short* __restrict__ Bt,
                                                 const float* __restrict__ bias,
                                                 unsigned short* __restrict__ qk_t,
                                                 unsigned short* __restrict__ v_nat) {
  __shared__ unsigned short smem[32768];  // 64 KiB: A 256x64 | B 256x64
  int tid = threadIdx.x, lane = tid & 63, wave = tid >> 6;
  int lr = lane & 15, lq = lane >> 4;
  // T1: bijective XCD swizzle over 1536 blocks (1536 % 8 == 0)
  int bid = blockIdx.y * 6 + blockIdx.x;
  int lid = (bid & 7) * 192 + (bid >> 3);
  int M0 = (lid % 6) * 256;
  size_t N0 = (size_t)(lid / 6) * 256;
  int wr = wave >> 2, wc = wave & 3;   // 2 x 4 wave grid; wave tile 128x64
  f32x4 acc[8][4] = {};

  const unsigned short* Abase = A + (size_t)M0 * 512;
  const unsigned short* Bbase = Bt + N0 * 512;

  // stage tile kt. LDS linear [256 rows][64 cols] bf16 (128B rows);
  // T2: source chunk pre-swizzled so reads XOR ((row&7)<<4) conflict-free.
  auto STAGE = [&](int kt) {
#pragma unroll
    for (int it = 0; it < 4; ++it) {
      int f = it * 512 + tid;
      int row = f >> 3;
      int cc = (f & 7) ^ (row & 7);
      const unsigned short* ga = Abase + (size_t)row * 512 + kt * 64 + cc * 8;
      gload_lds16(ga, smem + f * 8);
      const unsigned short* gb = Bbase + (size_t)row * 512 + kt * 64 + cc * 8;
      gload_lds16(gb, smem + 16384 + f * 8);
    }
  };

  for (int kt = 0; kt < 8; ++kt) {
    if (kt > 0) __syncthreads();            // all waves done reading tile kt-1
    STAGE(kt);
    asm volatile("s_waitcnt vmcnt(0)" ::: "memory");
    __syncthreads();                        // tile kt landed for all waves
    const char* Ad = (const char*)smem;
    const char* Bd = Ad + 32768;
#pragma unroll
    for (int ks = 0; ks < 2; ++ks) {
      bf16x8 af[8], bfr[4];
#pragma unroll
      for (int mf = 0; mf < 8; ++mf) {
        int r = wr * 128 + mf * 16 + lr;
        int c = ks * 64 + lq * 16;
        af[mf] = *(const bf16x8*)(Ad + r * 128 + (c ^ ((r & 7) << 4)));
      }
#pragma unroll
      for (int nf = 0; nf < 4; ++nf) {
        int r = wc * 64 + nf * 16 + lr;
        int c = ks * 64 + lq * 16;
        bfr[nf] = *(const bf16x8*)(Bd + r * 128 + (c ^ ((r & 7) << 4)));
      }
      __builtin_amdgcn_s_setprio(1);
#pragma unroll
      for (int mf = 0; mf < 8; ++mf)
#pragma unroll
        for (int nf = 0; nf < 4; ++nf)
          acc[mf][nf] = __builtin_amdgcn_mfma_f32_16x16x32_bf16(af[mf], bfr[nf], acc[mf][nf], 0, 0, 0);
      __builtin_amdgcn_s_setprio(0);
    }
  }

  // bias add: C row m = M0 + wr*128 + mf*16 + lq*4 + r
#pragma unroll
  for (int mf = 0; mf < 8; ++mf) {
    f32x4 bv = *(const f32x4*)(bias + M0 + wr * 128 + mf * 16 + lq * 4);
#pragma unroll
    for (int nf = 0; nf < 4; ++nf) acc[mf][nf] += bv;
  }

  __syncthreads();  // all reads of smem done before reuse
  if (M0 < 1024) {
    // q/k: transposed store via LDS, four n-quarters (Ct fits 64 KiB).
    // Ct[64 n][264 m-stride]
    unsigned short* Ct = smem;
    for (int q4 = 0; q4 < 4; ++q4) {
      __syncthreads();
      if (wc == q4) {
#pragma unroll
        for (int mf = 0; mf < 8; ++mf)
#pragma unroll
          for (int nf = 0; nf < 4; ++nf) {
            int n = nf * 16 + lr;
            int m = wr * 128 + mf * 16 + lq * 4;
            ushort4 pk;
            pk.x = f2bf(acc[mf][nf].x); pk.y = f2bf(acc[mf][nf].y);
            pk.z = f2bf(acc[mf][nf].z); pk.w = f2bf(acc[mf][nf].w);
            *(ushort4*)(Ct + n * 264 + m) = pk;
          }
      }
      __syncthreads();
      int n = tid >> 3, q = tid & 7;        // 64 rows x 8 chunks of 32B
      const unsigned short* src = Ct + n * 264 + q * 32;
      unsigned short* dst = qk_t + (N0 + q4 * 64 + n) * 1024 + M0 + q * 32;
#pragma unroll
      for (int ch = 0; ch < 4; ++ch)
        *(uint4*)(dst + ch * 8) = *(const uint4*)(src + ch * 8);
    }
  } else {
    // v: natural layout, scalar stores (16 lanes -> 32B contiguous, L2 combines)
#pragma unroll
    for (int mf = 0; mf < 8; ++mf)
#pragma unroll
      for (int nf = 0; nf < 4; ++nf) {
        int m = M0 - 1024 + wr * 128 + mf * 16 + lq * 4;
        size_t n = N0 + wc * 64 + nf * 16 + lr;
#pragma unroll
        for (int r = 0; r < 4; ++r)
          v_nat[(size_t)(m + r) * NPIX + n] = f2bf(acc[mf][nf][r]);
      }
  }
}

// ------------- attention v2: one block per (h, fixed), 32x32x16 MFMA --------
// 8 waves x 32 queries = 256 queries (whole row). Per wave:
//   S^T[j][i] = mfma32(K-frag, Q-frag)  (i = lane&31, j over 8 jt tiles)
//   softmax over j: 128 in-lane + 1 shfl_xor(32)
//   P-frags built IN-REGISTER: elem e of frag kt = S-reg r=(e&3)+4(2(kt&1)+hi)
//     from lane-half (e>>2)  ->  4 cvt_pk + 2 shfl_xor(32) per kt
//   O^T[i][d] = mfma32(P-frag, V-frag)  (V read from natural [d][j] LDS)
// PHASE 0: out1 = x + O (float4 stores) + out1^T bf16 via LDS transpose
// PHASE 1: colout_bt[c][fix*256+i] = bf16(O)  (ushort4 stores)
template <int PHASE>
__global__ __launch_bounds__(512) void k_attn2(const unsigned short* __restrict__ qk_t,
                                               const unsigned short* __restrict__ v_nat,
                                               const float* __restrict__ x,
                                               float* __restrict__ out1,
                                               unsigned short* __restrict__ out_bt) {
  __shared__ unsigned short smem[32768];      // 64 KiB: K^T 32K | V 32K; later Obt
  unsigned short* Ks = smem;                  // K^T [256 j][64 c], XOR-swizzled
  unsigned short* Vs = smem + 16384;          // V   [64 d][256 j], XOR-swizzled
  const int tid = threadIdx.x;
  const int lane = tid & 63, wave = tid >> 6;
  const int l31 = lane & 31, hi = lane >> 5;
  const int fix = blockIdx.x, h = blockIdx.y;
  const size_t pixbase = (size_t)fix * 256;
  const int i0w = wave * 32;

  // stage K^T (cols 512 + h*64 of qk_t rows)
#pragma unroll
  for (int it = 0; it < 4; ++it) {
    int f = it * 512 + tid;
    int j = f >> 3, ch = f & 7;
    uint4 val = *(const uint4*)(qk_t + (pixbase + j) * 1024 + 512 + h * 64 + ch * 8);
    *(uint4*)((char*)Ks + j * 128 + ((ch * 16) ^ ((j & 7) << 4))) = val;
  }
  // stage V
#pragma unroll
  for (int it = 0; it < 4; ++it) {
    int f = it * 512 + tid;
    int d = f >> 5, c2 = f & 31;
    uint4 val = *(const uint4*)(v_nat + (size_t)(h * 64 + d) * NPIX + pixbase + c2 * 8);
    *(uint4*)((char*)Vs + d * 512 + ((c2 * 16) ^ ((d & 7) << 4))) = val;
  }
  // Q fragments (B-operand): lane(hi, i=l31) holds Q[c = ks*16 + hi*8 + e][i]
  bf16x8 qf[4];
  {
    const unsigned short* qp = qk_t + (pixbase + i0w + l31) * 1024 + h * 64 + hi * 8;
#pragma unroll
    for (int ks = 0; ks < 4; ++ks) qf[ks] = *(const bf16x8*)(qp + ks * 16);
  }
  __syncthreads();

  // QK^T
  f32x16 s[8] = {};
  const int swz = (l31 & 7) << 4;
  __builtin_amdgcn_s_setprio(1);
#pragma unroll
  for (int jt = 0; jt < 8; ++jt) {
    const char* kr = (const char*)Ks + (jt * 32 + l31) * 128;
#pragma unroll
    for (int ks = 0; ks < 4; ++ks) {
      bf16x8 kf = *(const bf16x8*)(kr + ((ks * 32 + hi * 16) ^ swz));
      s[jt] = __builtin_amdgcn_mfma_f32_32x32x16_bf16(kf, qf[ks], s[jt], 0, 0, 0);
    }
  }
  __builtin_amdgcn_s_setprio(0);

  // softmax over j (row i = l31; 128 values in-lane, partner half has the rest)
  float mx = -3.4e38f;
#pragma unroll
  for (int jt = 0; jt < 8; ++jt)
#pragma unroll
    for (int r = 0; r < 16; ++r) mx = fmaxf(mx, s[jt][r]);
  mx = fmaxf(mx, __shfl_xor(mx, 32, 64));
  float sum = 0.f;
#pragma unroll
  for (int jt = 0; jt < 8; ++jt)
#pragma unroll
    for (int r = 0; r < 16; ++r) {
      float p = __expf(s[jt][r] - mx);
      s[jt][r] = p; sum += p;
    }
  sum += __shfl_xor(sum, 32, 64);
  float inv = 1.f / sum;

  // P fragments (A-operand for PV), normalized, in-register regroup
  bf16x8 pf[16];
#pragma unroll
  for (int jt = 0; jt < 8; ++jt)
#pragma unroll
    for (int kb = 0; kb < 2; ++kb) {
      int kt = jt * 2 + kb;
      unsigned pA0 = cvtpk(s[jt][kb * 8 + 0] * inv, s[jt][kb * 8 + 1] * inv);
      unsigned pA1 = cvtpk(s[jt][kb * 8 + 2] * inv, s[jt][kb * 8 + 3] * inv);
      unsigned pB0 = cvtpk(s[jt][kb * 8 + 4] * inv, s[jt][kb * 8 + 5] * inv);
      unsigned pB1 = cvtpk(s[jt][kb * 8 + 6] * inv, s[jt][kb * 8 + 7] * inv);
      // half-0 sends its B-quad (needed by hi=1 targets); half-1 sends its A-quad
      unsigned s0 = hi ? pA0 : pB0;
      unsigned s1 = hi ? pA1 : pB1;
      unsigned r0 = (unsigned)__shfl_xor((int)s0, 32, 64);
      unsigned r1 = (unsigned)__shfl_xor((int)s1, 32, 64);
      union { unsigned u[4]; bf16x8 v; } pk_;
      pk_.u[0] = hi ? r0 : pA0;   // e0,e1 (from half-0, quad 2kb+hi)
      pk_.u[1] = hi ? r1 : pA1;   // e2,e3
      pk_.u[2] = hi ? pB0 : r0;   // e4,e5 (from half-1, quad 2kb+hi)
      pk_.u[3] = hi ? pB1 : r1;   // e6,e7
      pf[kt] = pk_.v;
    }

  // PV: O^T[i][d]
  f32x16 o[2] = {};
  __builtin_amdgcn_s_setprio(1);
#pragma unroll
  for (int dt = 0; dt < 2; ++dt) {
    const char* vr = (const char*)Vs + (dt * 32 + l31) * 512;
#pragma unroll
    for (int kt = 0; kt < 16; ++kt) {
      bf16x8 vf = *(const bf16x8*)(vr + ((kt * 32 + hi * 16) ^ swz));
      o[dt] = __builtin_amdgcn_mfma_f32_32x32x16_bf16(pf[kt], vf, o[dt], 0, 0, 0);
    }
  }
  __builtin_amdgcn_s_setprio(0);

  // epilogue: lane(hi, d=dt*32+l31) holds O^T[i = q*8 + hi*4 + m][d], reg 4q+m
  if (PHASE == 0) {
#pragma unroll
    for (int dt = 0; dt < 2; ++dt) {
      int c = h * 64 + dt * 32 + l31;
      float* ob = out1 + (size_t)c * NPIX + pixbase + i0w;
      const float* xb = x + (size_t)c * NPIX + pixbase + i0w;
#pragma unroll
      for (int q = 0; q < 4; ++q) {
        int ib = q * 8 + hi * 4;
        float4 xv = *(const float4*)(xb + ib);
        float4 vv;
        vv.x = o[dt][q * 4 + 0] + xv.x;
        vv.y = o[dt][q * 4 + 1] + xv.y;
        vv.z = o[dt][q * 4 + 2] + xv.z;
        vv.w = o[dt][q * 4 + 3] + xv.w;
        *(float4*)(ob + ib) = vv;
        o[dt][q * 4 + 0] = vv.x; o[dt][q * 4 + 1] = vv.y;
        o[dt][q * 4 + 2] = vv.z; o[dt][q * 4 + 3] = vv.w;
      }
    }
    __syncthreads();                       // K/V reads done -> overlay Obt
    unsigned short* Obt = smem;            // [256 i][72 d] (72 for 16B-aligned rows)
#pragma unroll
    for (int dt = 0; dt < 2; ++dt) {
      int d = dt * 32 + l31;
#pragma unroll
      for (int q = 0; q < 4; ++q)
#pragma unroll
        for (int m = 0; m < 4; ++m)
          Obt[(i0w + q * 8 + hi * 4 + m) * 72 + d] = f2bf(o[dt][q * 4 + m]);
    }
    __syncthreads();
    int row = tid >> 1, half = tid & 1;
    const unsigned short* src = Obt + row * 72 + half * 32;
    unsigned short* dst = out_bt + ((size_t)row * 256 + fix) * 512 + h * 64 + half * 32;
#pragma unroll
    for (int c4 = 0; c4 < 4; ++c4)
      *(uint4*)(dst + c4 * 8) = *(const uint4*)(src + c4 * 8);
  } else {
#pragma unroll
    for (int dt = 0; dt < 2; ++dt) {
      int c = h * 64 + dt * 32 + l31;
      unsigned short* ob = out_bt + (size_t)c * NPIX + pixbase + i0w;
#pragma unroll
      for (int q = 0; q < 4; ++q) {
        ushort4 pkv;
        pkv.x = f2bf(o[dt][q * 4 + 0]);
        pkv.y = f2bf(o[dt][q * 4 + 1]);
        pkv.z = f2bf(o[dt][q * 4 + 2]);
        pkv.w = f2bf(o[dt][q * 4 + 3]);
        *(ushort4*)(ob + q * 8 + hi * 4) = pkv;
      }
    }
  }
}

// --------- final: out[c][s][l] += colout_bt[c][l][s] (LDS transpose-add) ----
__global__ __launch_bounds__(256) void k_final(const unsigned short* __restrict__ colt,
                                               float* __restrict__ out) {
  __shared__ unsigned short Xs[64 * 68];
  int c = blockIdx.y;
  int lt = blockIdx.x & 3, st = blockIdx.x >> 2;
  int l0 = lt * 64, s0 = st * 64;
  int t = threadIdx.x;
  for (int rep = 0; rep < 4; ++rep) {
    int f = rep * 256 + t, li = f >> 4, jj = f & 15;
    ushort4 v = *(const ushort4*)(colt + (size_t)c * NPIX + (size_t)(l0 + li) * 256 + s0 + jj * 4);
    *(ushort4*)(Xs + li * 68 + jj * 4) = v;
  }
  __syncthreads();
  int si = t >> 2, q = t & 3;
  float* drow = out + (size_t)c * NPIX + (size_t)(s0 + si) * 256 + l0 + q * 16;
  for (int h4 = 0; h4 < 4; ++h4) {
    float4 a = *(float4*)(drow + h4 * 4);
    a.x += bf2f(Xs[(q * 16 + h4 * 4 + 0) * 68 + si]);
    a.y += bf2f(Xs[(q * 16 + h4 * 4 + 1) * 68 + si]);
    a.z += bf2f(Xs[(q * 16 + h4 * 4 + 2) * 68 + si]);
    a.w += bf2f(Xs[(q * 16 + h4 * 4 + 3) * 68 + si]);
    *(float4*)(drow + h4 * 4) = a;
  }
}

extern "C" void kernel_launch(void* const* d_in, const int* in_sizes, int n_in,
                              void* d_out, int out_size, void* d_ws, size_t ws_size,
                              hipStream_t stream) {
  const float* x  = (const float*)d_in[0];
  const float* Wr = (const float*)d_in[1];
  const float* br = (const float*)d_in[2];
  const float* Wc = (const float*)d_in[3];
  const float* bc = (const float*)d_in[4];
  float* out = (float*)d_out;
  char* ws = (char*)d_ws;
  unsigned short* qk_t  = (unsigned short*)(ws);                            // 128 MB [65536][1024]
  unsigned short* v_nat = (unsigned short*)(ws + 134217728);                // 64 MB  [512][65536]
  unsigned short* scr3  = (unsigned short*)(ws + 134217728 + 67108864);     // 64 MB  x^T / out1bt / colout
  unsigned short* Wrb   = (unsigned short*)(ws + 268435456);                // 1.5 MB
  unsigned short* Wcb   = (unsigned short*)(ws + 268435456 + 1572864);      // 1.5 MB

  k_cvt<<<768, 256, 0, stream>>>(Wr, Wrb, 196608);
  k_cvt<<<768, 256, 0, stream>>>(Wc, Wcb, 196608);
  k_cvt_transpose<<<dim3(1024, 8), 256, 0, stream>>>(x, scr3);              // scr3 = x^T bf16
  k_gemm<<<dim3(6, 256), 512, 0, stream>>>(Wrb, scr3, br, qk_t, v_nat);     // row QKV
  k_attn2<0><<<dim3(256, 8), 512, 0, stream>>>(qk_t, v_nat, x, out, scr3);  // out=out1, scr3=out1^T bf16
  k_gemm<<<dim3(6, 256), 512, 0, stream>>>(Wcb, scr3, bc, qk_t, v_nat);     // col QKV
  k_attn2<1><<<dim3(256, 8), 512, 0, stream>>>(qk_t, v_nat, nullptr, nullptr, scr3); // scr3=colout
  k_final<<<dim3(16, 512), 256, 0, stream>>>(scr3, out);                    // out += colout^T
}

// Round 8
// 681.716 us; speedup vs baseline: 3.7043x; 3.7043x over previous
//
#include <hip/hip_runtime.h>

typedef __bf16 bf16_t;
typedef __attribute__((ext_vector_type(8))) __bf16 bf16x8;
typedef __attribute__((ext_vector_type(4))) float f32x4;
typedef __attribute__((ext_vector_type(16))) float f32x16;

#define NH   8
#define DH   64
#define DD   512
#define NPIX 65536   // 256*256

__device__ __forceinline__ unsigned short f2bf(float f) {
  unsigned int u = __builtin_bit_cast(unsigned int, f);
  u += 0x7fffu + ((u >> 16) & 1u);
  return (unsigned short)(u >> 16);
}
__device__ __forceinline__ float bf2f(unsigned short b) {
  return __builtin_bit_cast(float, ((unsigned int)b) << 16);
}
__device__ __forceinline__ unsigned cvtpk(float a, float b) {
  unsigned r;
  asm("v_cvt_pk_bf16_f32 %0, %1, %2" : "=v"(r) : "v"(a), "v"(b));
  return r;
}

__device__ __forceinline__ void gload_lds16(const void* g, void* l) {
  __builtin_amdgcn_global_load_lds(
      (const __attribute__((address_space(1))) void*)(uintptr_t)g,
      (__attribute__((address_space(3))) void*)(uintptr_t)l, 16, 0, 0);
}

// ---------------- elementwise fp32 -> bf16 convert (weights) ----------------
__global__ __launch_bounds__(256) void k_cvt(const float* __restrict__ in,
                                             unsigned short* __restrict__ out, int n4) {
  int i = blockIdx.x * 256 + threadIdx.x;
  if (i >= n4) return;
  float4 v = ((const float4*)in)[i];
  ushort4 o; o.x = f2bf(v.x); o.y = f2bf(v.y); o.z = f2bf(v.z); o.w = f2bf(v.w);
  ((ushort4*)out)[i] = o;
}

// ------------- x [512][65536] f32 -> x^T [65536][512] bf16 ------------------
__global__ __launch_bounds__(256) void k_cvt_transpose(const float* __restrict__ x,
                                                       unsigned short* __restrict__ xt) {
  __shared__ unsigned short Xs[64 * 68];
  int p0 = blockIdx.x * 64, c0 = blockIdx.y * 64;
  int t = threadIdx.x;
  for (int rep = 0; rep < 4; ++rep) {
    int f = rep * 256 + t, i = f >> 4, jj = f & 15;
    float4 v = *(const float4*)(x + (size_t)(c0 + i) * NPIX + p0 + jj * 4);
    ushort4 o; o.x = f2bf(v.x); o.y = f2bf(v.y); o.z = f2bf(v.z); o.w = f2bf(v.w);
    *(ushort4*)(Xs + i * 68 + jj * 4) = o;
  }
  __syncthreads();
  int j = t >> 2, q = t & 3;
  unsigned short* dst = xt + (size_t)(p0 + j) * DD + c0 + q * 16;
  for (int h2 = 0; h2 < 2; ++h2) {
    union { unsigned short u[8]; uint4 v; } pk;
    for (int cc = 0; cc < 8; ++cc) pk.u[cc] = Xs[(q * 16 + h2 * 8 + cc) * 68 + j];
    *(uint4*)(dst + h2 * 8) = pk.v;
  }
}

// ---------------- GEMM: C[1536][65536] = W[1536][512] @ X + b ---------------
// 256x256 tile, BK=64, 8 waves (2Mx4N). SINGLE-buffered 64 KiB LDS so TWO
// blocks co-reside per CU (launch_bounds(512,2): 128 VGPR, 16 waves/CU):
// one block's stage+vmcnt stall hides under the partner block's MFMA phase.
// Per K-tile: barrier -> STAGE(kt) -> vmcnt(0)+barrier -> ds_reads + MFMA.
__global__ __launch_bounds__(512, 2) void k_gemm(const unsigned short* __restrict__ A,
                                                 const unsigned short* __restrict__ Bt,
                                                 const float* __restrict__ bias,
                                                 unsigned short* __restrict__ qk_t,
                                                 unsigned short* __restrict__ v_nat) {
  __shared__ unsigned short smem[32768];  // 64 KiB: A 256x64 | B 256x64
  int tid = threadIdx.x, lane = tid & 63, wave = tid >> 6;
  int lr = lane & 15, lq = lane >> 4;
  // T1: bijective XCD swizzle over 1536 blocks (1536 % 8 == 0)
  int bid = blockIdx.y * 6 + blockIdx.x;
  int lid = (bid & 7) * 192 + (bid >> 3);
  int M0 = (lid % 6) * 256;
  size_t N0 = (size_t)(lid / 6) * 256;
  int wr = wave >> 2, wc = wave & 3;   // 2 x 4 wave grid; wave tile 128x64
  f32x4 acc[8][4] = {};

  const unsigned short* Abase = A + (size_t)M0 * 512;
  const unsigned short* Bbase = Bt + N0 * 512;

  // stage tile kt. LDS linear [256 rows][64 cols] bf16 (128B rows);
  // T2: source chunk pre-swizzled so reads XOR ((row&7)<<4) conflict-free.
  auto STAGE = [&](int kt) {
#pragma unroll
    for (int it = 0; it < 4; ++it) {
      int f = it * 512 + tid;
      int row = f >> 3;
      int cc = (f & 7) ^ (row & 7);
      const unsigned short* ga = Abase + (size_t)row * 512 + kt * 64 + cc * 8;
      gload_lds16(ga, smem + f * 8);
      const unsigned short* gb = Bbase + (size_t)row * 512 + kt * 64 + cc * 8;
      gload_lds16(gb, smem + 16384 + f * 8);
    }
  };

  for (int kt = 0; kt < 8; ++kt) {
    if (kt > 0) __syncthreads();            // all waves done reading tile kt-1
    STAGE(kt);
    asm volatile("s_waitcnt vmcnt(0)" ::: "memory");
    __syncthreads();                        // tile kt landed for all waves
    const char* Ad = (const char*)smem;
    const char* Bd = Ad + 32768;
#pragma unroll
    for (int ks = 0; ks < 2; ++ks) {
      bf16x8 af[8], bfr[4];
#pragma unroll
      for (int mf = 0; mf < 8; ++mf) {
        int r = wr * 128 + mf * 16 + lr;
        int c = ks * 64 + lq * 16;
        af[mf] = *(const bf16x8*)(Ad + r * 128 + (c ^ ((r & 7) << 4)));
      }
#pragma unroll
      for (int nf = 0; nf < 4; ++nf) {
        int r = wc * 64 + nf * 16 + lr;
        int c = ks * 64 + lq * 16;
        bfr[nf] = *(const bf16x8*)(Bd + r * 128 + (c ^ ((r & 7) << 4)));
      }
      __builtin_amdgcn_s_setprio(1);
#pragma unroll
      for (int mf = 0; mf < 8; ++mf)
#pragma unroll
        for (int nf = 0; nf < 4; ++nf)
          acc[mf][nf] = __builtin_amdgcn_mfma_f32_16x16x32_bf16(af[mf], bfr[nf], acc[mf][nf], 0, 0, 0);
      __builtin_amdgcn_s_setprio(0);
    }
  }

  // bias add: C row m = M0 + wr*128 + mf*16 + lq*4 + r
#pragma unroll
  for (int mf = 0; mf < 8; ++mf) {
    f32x4 bv = *(const f32x4*)(bias + M0 + wr * 128 + mf * 16 + lq * 4);
#pragma unroll
    for (int nf = 0; nf < 4; ++nf) acc[mf][nf] += bv;
  }

  __syncthreads();  // all reads of smem done before reuse
  if (M0 < 1024) {
    // q/k: transposed store via LDS, four n-quarters (Ct fits 64 KiB).
    // Ct[64 n][264 m-stride]
    unsigned short* Ct = smem;
    for (int q4 = 0; q4 < 4; ++q4) {
      __syncthreads();
      if (wc == q4) {
#pragma unroll
        for (int mf = 0; mf < 8; ++mf)
#pragma unroll
          for (int nf = 0; nf < 4; ++nf) {
            int n = nf * 16 + lr;
            int m = wr * 128 + mf * 16 + lq * 4;
            ushort4 pk;
            pk.x = f2bf(acc[mf][nf].x); pk.y = f2bf(acc[mf][nf].y);
            pk.z = f2bf(acc[mf][nf].z); pk.w = f2bf(acc[mf][nf].w);
            *(ushort4*)(Ct + n * 264 + m) = pk;
          }
      }
      __syncthreads();
      int n = tid >> 3, q = tid & 7;        // 64 rows x 8 chunks of 32B
      const unsigned short* src = Ct + n * 264 + q * 32;
      unsigned short* dst = qk_t + (N0 + q4 * 64 + n) * 1024 + M0 + q * 32;
#pragma unroll
      for (int ch = 0; ch < 4; ++ch)
        *(uint4*)(dst + ch * 8) = *(const uint4*)(src + ch * 8);
    }
  } else {
    // v: natural layout, scalar stores (16 lanes -> 32B contiguous, L2 combines)
#pragma unroll
    for (int mf = 0; mf < 8; ++mf)
#pragma unroll
      for (int nf = 0; nf < 4; ++nf) {
        int m = M0 - 1024 + wr * 128 + mf * 16 + lq * 4;
        size_t n = N0 + wc * 64 + nf * 16 + lr;
#pragma unroll
        for (int r = 0; r < 4; ++r)
          v_nat[(size_t)(m + r) * NPIX + n] = f2bf(acc[mf][nf][r]);
      }
  }
}

// ------------- attention v2: one block per (h, fixed), 32x32x16 MFMA --------
// 8 waves x 32 queries = 256 queries (whole row). Per wave:
//   S^T[j][i] = mfma32(K-frag, Q-frag)  (i = lane&31, j over 8 jt tiles)
//   softmax over j: 128 in-lane + 1 shfl_xor(32)
//   P-frags built IN-REGISTER: elem e of frag kt = S-reg r=(e&3)+4(2(kt&1)+hi)
//     from lane-half (e>>2)  ->  4 cvt_pk + 2 shfl_xor(32) per kt
//   O^T[i][d] = mfma32(P-frag, V-frag)  (V read from natural [d][j] LDS)
// PHASE 0: out1 = x + O (float4 stores) + out1^T bf16 via LDS transpose
// PHASE 1: colout_bt[c][fix*256+i] = bf16(O)  (ushort4 stores)
template <int PHASE>
__global__ __launch_bounds__(512) void k_attn2(const unsigned short* __restrict__ qk_t,
                                               const unsigned short* __restrict__ v_nat,
                                               const float* __restrict__ x,
                                               float* __restrict__ out1,
                                               unsigned short* __restrict__ out_bt) {
  __shared__ unsigned short smem[32768];      // 64 KiB: K^T 32K | V 32K; later Obt
  unsigned short* Ks = smem;                  // K^T [256 j][64 c], XOR-swizzled
  unsigned short* Vs = smem + 16384;          // V   [64 d][256 j], XOR-swizzled
  const int tid = threadIdx.x;
  const int lane = tid & 63, wave = tid >> 6;
  const int l31 = lane & 31, hi = lane >> 5;
  const int fix = blockIdx.x, h = blockIdx.y;
  const size_t pixbase = (size_t)fix * 256;
  const int i0w = wave * 32;

  // stage K^T (cols 512 + h*64 of qk_t rows)
#pragma unroll
  for (int it = 0; it < 4; ++it) {
    int f = it * 512 + tid;
    int j = f >> 3, ch = f & 7;
    uint4 val = *(const uint4*)(qk_t + (pixbase + j) * 1024 + 512 + h * 64 + ch * 8);
    *(uint4*)((char*)Ks + j * 128 + ((ch * 16) ^ ((j & 7) << 4))) = val;
  }
  // stage V
#pragma unroll
  for (int it = 0; it < 4; ++it) {
    int f = it * 512 + tid;
    int d = f >> 5, c2 = f & 31;
    uint4 val = *(const uint4*)(v_nat + (size_t)(h * 64 + d) * NPIX + pixbase + c2 * 8);
    *(uint4*)((char*)Vs + d * 512 + ((c2 * 16) ^ ((d & 7) << 4))) = val;
  }
  // Q fragments (B-operand): lane(hi, i=l31) holds Q[c = ks*16 + hi*8 + e][i]
  bf16x8 qf[4];
  {
    const unsigned short* qp = qk_t + (pixbase + i0w + l31) * 1024 + h * 64 + hi * 8;
#pragma unroll
    for (int ks = 0; ks < 4; ++ks) qf[ks] = *(const bf16x8*)(qp + ks * 16);
  }
  __syncthreads();

  // QK^T
  f32x16 s[8] = {};
  const int swz = (l31 & 7) << 4;
  __builtin_amdgcn_s_setprio(1);
#pragma unroll
  for (int jt = 0; jt < 8; ++jt) {
    const char* kr = (const char*)Ks + (jt * 32 + l31) * 128;
#pragma unroll
    for (int ks = 0; ks < 4; ++ks) {
      bf16x8 kf = *(const bf16x8*)(kr + ((ks * 32 + hi * 16) ^ swz));
      s[jt] = __builtin_amdgcn_mfma_f32_32x32x16_bf16(kf, qf[ks], s[jt], 0, 0, 0);
    }
  }
  __builtin_amdgcn_s_setprio(0);

  // softmax over j (row i = l31; 128 values in-lane, partner half has the rest)
  float mx = -3.4e38f;
#pragma unroll
  for (int jt = 0; jt < 8; ++jt)
#pragma unroll
    for (int r = 0; r < 16; ++r) mx = fmaxf(mx, s[jt][r]);
  mx = fmaxf(mx, __shfl_xor(mx, 32, 64));
  float sum = 0.f;
#pragma unroll
  for (int jt = 0; jt < 8; ++jt)
#pragma unroll
    for (int r = 0; r < 16; ++r) {
      float p = __expf(s[jt][r] - mx);
      s[jt][r] = p; sum += p;
    }
  sum += __shfl_xor(sum, 32, 64);
  float inv = 1.f / sum;

  // P fragments (A-operand for PV), normalized, in-register regroup
  bf16x8 pf[16];
#pragma unroll
  for (int jt = 0; jt < 8; ++jt)
#pragma unroll
    for (int kb = 0; kb < 2; ++kb) {
      int kt = jt * 2 + kb;
      unsigned pA0 = cvtpk(s[jt][kb * 8 + 0] * inv, s[jt][kb * 8 + 1] * inv);
      unsigned pA1 = cvtpk(s[jt][kb * 8 + 2] * inv, s[jt][kb * 8 + 3] * inv);
      unsigned pB0 = cvtpk(s[jt][kb * 8 + 4] * inv, s[jt][kb * 8 + 5] * inv);
      unsigned pB1 = cvtpk(s[jt][kb * 8 + 6] * inv, s[jt][kb * 8 + 7] * inv);
      // half-0 sends its B-quad (needed by hi=1 targets); half-1 sends its A-quad
      unsigned s0 = hi ? pA0 : pB0;
      unsigned s1 = hi ? pA1 : pB1;
      unsigned r0 = (unsigned)__shfl_xor((int)s0, 32, 64);
      unsigned r1 = (unsigned)__shfl_xor((int)s1, 32, 64);
      union { unsigned u[4]; bf16x8 v; } pk_;
      pk_.u[0] = hi ? r0 : pA0;   // e0,e1 (from half-0, quad 2kb+hi)
      pk_.u[1] = hi ? r1 : pA1;   // e2,e3
      pk_.u[2] = hi ? pB0 : r0;   // e4,e5 (from half-1, quad 2kb+hi)
      pk_.u[3] = hi ? pB1 : r1;   // e6,e7
      pf[kt] = pk_.v;
    }

  // PV: O^T[i][d]
  f32x16 o[2] = {};
  __builtin_amdgcn_s_setprio(1);
#pragma unroll
  for (int dt = 0; dt < 2; ++dt) {
    const char* vr = (const char*)Vs + (dt * 32 + l31) * 512;
#pragma unroll
    for (int kt = 0; kt < 16; ++kt) {
      bf16x8 vf = *(const bf16x8*)(vr + ((kt * 32 + hi * 16) ^ swz));
      o[dt] = __builtin_amdgcn_mfma_f32_32x32x16_bf16(pf[kt], vf, o[dt], 0, 0, 0);
    }
  }
  __builtin_amdgcn_s_setprio(0);

  // epilogue: lane(hi, d=dt*32+l31) holds O^T[i = q*8 + hi*4 + m][d], reg 4q+m
  if (PHASE == 0) {
#pragma unroll
    for (int dt = 0; dt < 2; ++dt) {
      int c = h * 64 + dt * 32 + l31;
      float* ob = out1 + (size_t)c * NPIX + pixbase + i0w;
      const float* xb = x + (size_t)c * NPIX + pixbase + i0w;
#pragma unroll
      for (int q = 0; q < 4; ++q) {
        int ib = q * 8 + hi * 4;
        float4 xv = *(const float4*)(xb + ib);
        float4 vv;
        vv.x = o[dt][q * 4 + 0] + xv.x;
        vv.y = o[dt][q * 4 + 1] + xv.y;
        vv.z = o[dt][q * 4 + 2] + xv.z;
        vv.w = o[dt][q * 4 + 3] + xv.w;
        *(float4*)(ob + ib) = vv;
        o[dt][q * 4 + 0] = vv.x; o[dt][q * 4 + 1] = vv.y;
        o[dt][q * 4 + 2] = vv.z; o[dt][q * 4 + 3] = vv.w;
      }
    }
    __syncthreads();                       // K/V reads done -> overlay Obt
    unsigned short* Obt = smem;            // [256 i][72 d] (72 for 16B-aligned rows)
#pragma unroll
    for (int dt = 0; dt < 2; ++dt) {
      int d = dt * 32 + l31;
#pragma unroll
      for (int q = 0; q < 4; ++q)
#pragma unroll
        for (int m = 0; m < 4; ++m)
          Obt[(i0w + q * 8 + hi * 4 + m) * 72 + d] = f2bf(o[dt][q * 4 + m]);
    }
    __syncthreads();
    int row = tid >> 1, half = tid & 1;
    const unsigned short* src = Obt + row * 72 + half * 32;
    unsigned short* dst = out_bt + ((size_t)row * 256 + fix) * 512 + h * 64 + half * 32;
#pragma unroll
    for (int c4 = 0; c4 < 4; ++c4)
      *(uint4*)(dst + c4 * 8) = *(const uint4*)(src + c4 * 8);
  } else {
#pragma unroll
    for (int dt = 0; dt < 2; ++dt) {
      int c = h * 64 + dt * 32 + l31;
      unsigned short* ob = out_bt + (size_t)c * NPIX + pixbase + i0w;
#pragma unroll
      for (int q = 0; q < 4; ++q) {
        ushort4 pkv;
        pkv.x = f2bf(o[dt][q * 4 + 0]);
        pkv.y = f2bf(o[dt][q * 4 + 1]);
        pkv.z = f2bf(o[dt][q * 4 + 2]);
        pkv.w = f2bf(o[dt][q * 4 + 3]);
        *(ushort4*)(ob + q * 8 + hi * 4) = pkv;
      }
    }
  }
}

// --------- final: out[c][s][l] += colout_bt[c][l][s] (LDS transpose-add) ----
__global__ __launch_bounds__(256) void k_final(const unsigned short* __restrict__ colt,
                                               float* __restrict__ out) {
  __shared__ unsigned short Xs[64 * 68];
  int c = blockIdx.y;
  int lt = blockIdx.x & 3, st = blockIdx.x >> 2;
  int l0 = lt * 64, s0 = st * 64;
  int t = threadIdx.x;
  for (int rep = 0; rep < 4; ++rep) {
    int f = rep * 256 + t, li = f >> 4, jj = f & 15;
    ushort4 v = *(const ushort4*)(colt + (size_t)c * NPIX + (size_t)(l0 + li) * 256 + s0 + jj * 4);
    *(ushort4*)(Xs + li * 68 + jj * 4) = v;
  }
  __syncthreads();
  int si = t >> 2, q = t & 3;
  float* drow = out + (size_t)c * NPIX + (size_t)(s0 + si) * 256 + l0 + q * 16;
  for (int h4 = 0; h4 < 4; ++h4) {
    float4 a = *(float4*)(drow + h4 * 4);
    a.x += bf2f(Xs[(q * 16 + h4 * 4 + 0) * 68 + si]);
    a.y += bf2f(Xs[(q * 16 + h4 * 4 + 1) * 68 + si]);
    a.z += bf2f(Xs[(q * 16 + h4 * 4 + 2) * 68 + si]);
    a.w += bf2f(Xs[(q * 16 + h4 * 4 + 3) * 68 + si]);
    *(float4*)(drow + h4 * 4) = a;
  }
}

extern "C" void kernel_launch(void* const* d_in, const int* in_sizes, int n_in,
                              void* d_out, int out_size, void* d_ws, size_t ws_size,
                              hipStream_t stream) {
  const float* x  = (const float*)d_in[0];
  const float* Wr = (const float*)d_in[1];
  const float* br = (const float*)d_in[2];
  const float* Wc = (const float*)d_in[3];
  const float* bc = (const float*)d_in[4];
  float* out = (float*)d_out;
  char* ws = (char*)d_ws;
  unsigned short* qk_t  = (unsigned short*)(ws);                            // 128 MB [65536][1024]
  unsigned short* v_nat = (unsigned short*)(ws + 134217728);                // 64 MB  [512][65536]
  unsigned short* scr3  = (unsigned short*)(ws + 134217728 + 67108864);     // 64 MB  x^T / out1bt / colout
  unsigned short* Wrb   = (unsigned short*)(ws + 268435456);                // 1.5 MB
  unsigned short* Wcb   = (unsigned short*)(ws + 268435456 + 1572864);      // 1.5 MB

  k_cvt<<<768, 256, 0, stream>>>(Wr, Wrb, 196608);
  k_cvt<<<768, 256, 0, stream>>>(Wc, Wcb, 196608);
  k_cvt_transpose<<<dim3(1024, 8), 256, 0, stream>>>(x, scr3);              // scr3 = x^T bf16
  k_gemm<<<dim3(6, 256), 512, 0, stream>>>(Wrb, scr3, br, qk_t, v_nat);     // row QKV
  k_attn2<0><<<dim3(256, 8), 512, 0, stream>>>(qk_t, v_nat, x, out, scr3);  // out=out1, scr3=out1^T bf16
  k_gemm<<<dim3(6, 256), 512, 0, stream>>>(Wcb, scr3, bc, qk_t, v_nat);     // col QKV
  k_attn2<1><<<dim3(256, 8), 512, 0, stream>>>(qk_t, v_nat, nullptr, nullptr, scr3); // scr3=colout
  k_final<<<dim3(16, 512), 256, 0, stream>>>(scr3, out);                    // out += colout^T
}

// Round 9
// 616.328 us; speedup vs baseline: 4.0973x; 1.1061x over previous
//
#include <hip/hip_runtime.h>

typedef __bf16 bf16_t;
typedef __attribute__((ext_vector_type(8))) __bf16 bf16x8;
typedef __attribute__((ext_vector_type(4))) float f32x4;
typedef __attribute__((ext_vector_type(16))) float f32x16;

#define NH   8
#define DH   64
#define DD   512
#define NPIX 65536   // 256*256

__device__ __forceinline__ unsigned short f2bf(float f) {
  unsigned int u = __builtin_bit_cast(unsigned int, f);
  u += 0x7fffu + ((u >> 16) & 1u);
  return (unsigned short)(u >> 16);
}
__device__ __forceinline__ float bf2f(unsigned short b) {
  return __builtin_bit_cast(float, ((unsigned int)b) << 16);
}
__device__ __forceinline__ unsigned cvtpk(float a, float b) {
  unsigned r;
  asm("v_cvt_pk_bf16_f32 %0, %1, %2" : "=v"(r) : "v"(a), "v"(b));
  return r;
}

__device__ __forceinline__ void gload_lds16(const void* g, void* l) {
  __builtin_amdgcn_global_load_lds(
      (const __attribute__((address_space(1))) void*)(uintptr_t)g,
      (__attribute__((address_space(3))) void*)(uintptr_t)l, 16, 0, 0);
}

// ---------------- elementwise fp32 -> bf16 convert (weights) ----------------
__global__ __launch_bounds__(256) void k_cvt(const float* __restrict__ in,
                                             unsigned short* __restrict__ out, int n4) {
  int i = blockIdx.x * 256 + threadIdx.x;
  if (i >= n4) return;
  float4 v = ((const float4*)in)[i];
  ushort4 o; o.x = f2bf(v.x); o.y = f2bf(v.y); o.z = f2bf(v.z); o.w = f2bf(v.w);
  ((ushort4*)out)[i] = o;
}

// ------------- x [512][65536] f32 -> x^T [65536][512] bf16 ------------------
__global__ __launch_bounds__(256) void k_cvt_transpose(const float* __restrict__ x,
                                                       unsigned short* __restrict__ xt) {
  __shared__ unsigned short Xs[64 * 68];
  int p0 = blockIdx.x * 64, c0 = blockIdx.y * 64;
  int t = threadIdx.x;
  for (int rep = 0; rep < 4; ++rep) {
    int f = rep * 256 + t, i = f >> 4, jj = f & 15;
    float4 v = *(const float4*)(x + (size_t)(c0 + i) * NPIX + p0 + jj * 4);
    ushort4 o; o.x = f2bf(v.x); o.y = f2bf(v.y); o.z = f2bf(v.z); o.w = f2bf(v.w);
    *(ushort4*)(Xs + i * 68 + jj * 4) = o;
  }
  __syncthreads();
  int j = t >> 2, q = t & 3;
  unsigned short* dst = xt + (size_t)(p0 + j) * DD + c0 + q * 16;
  for (int h2 = 0; h2 < 2; ++h2) {
    union { unsigned short u[8]; uint4 v; } pk;
    for (int cc = 0; cc < 8; ++cc) pk.u[cc] = Xs[(q * 16 + h2 * 8 + cc) * 68 + j];
    *(uint4*)(dst + h2 * 8) = pk.v;
  }
}

// ---------------- GEMM: C[1536][65536] = W[1536][512] @ X + b ---------------
// 128x128 tile, BK=64, 4 waves (2x2, wave tile 64x64, acc=64 AGPR).
// Single-buffered 36 KiB LDS + ~150 total regs -> THREE blocks/CU co-resident
// (launch_bounds(256,3)): one block's stage+vmcnt(0) drain hides under the
// partner blocks' MFMA phases. Grid 12x512 = 6144 blocks = 24/CU.
// T1 chunked-XCD swizzle (12 M-blocks share a B-slab on one XCD's L2);
// T2 both-sides swizzle (pre-swizzled global source, XOR'd ds_read).
__global__ __launch_bounds__(256, 3) void k_gemm(const unsigned short* __restrict__ A,
                                                 const unsigned short* __restrict__ Bt,
                                                 const float* __restrict__ bias,
                                                 unsigned short* __restrict__ qk_t,
                                                 unsigned short* __restrict__ v_nat) {
  __shared__ unsigned short smem[18432];  // 36 KiB: A 128x64 (16K) | B 128x64 (16K); Ct 34.8K
  int tid = threadIdx.x, lane = tid & 63, wave = tid >> 6;
  int lr = lane & 15, lq = lane >> 4;
  // T1: bijective XCD swizzle over 6144 blocks (6144 % 8 == 0)
  int bid = blockIdx.y * 12 + blockIdx.x;
  int lid = (bid & 7) * 768 + (bid >> 3);
  int M0 = (lid % 12) * 128;
  size_t N0 = (size_t)(lid / 12) * 128;
  int wr = wave >> 1, wc = wave & 1;   // 2 x 2 wave grid; wave tile 64x64
  f32x4 acc[4][4] = {};

  const unsigned short* Abase = A + (size_t)M0 * 512;
  const unsigned short* Bbase = Bt + N0 * 512;

  // stage tile kt (A 16KB + B 16KB). LDS linear [128 rows][64 cols] per matrix;
  // T2: source chunk pre-swizzled so reads XOR ((row&7)<<4) conflict-free.
  auto STAGE = [&](int kt) {
#pragma unroll
    for (int it = 0; it < 4; ++it) {
      int f = it * 256 + tid;          // 0..1023: row=f>>3 (0..127), chunk=f&7
      int row = f >> 3;
      int cc = (f & 7) ^ (row & 7);
      const unsigned short* ga = Abase + (size_t)row * 512 + kt * 64 + cc * 8;
      gload_lds16(ga, smem + f * 8);
      const unsigned short* gb = Bbase + (size_t)row * 512 + kt * 64 + cc * 8;
      gload_lds16(gb, smem + 8192 + f * 8);
    }
  };

  for (int kt = 0; kt < 8; ++kt) {
    if (kt > 0) __syncthreads();            // all waves done reading tile kt-1
    STAGE(kt);
    asm volatile("s_waitcnt vmcnt(0)" ::: "memory");
    __syncthreads();                        // tile kt landed for all waves
    const char* Ad = (const char*)smem;
    const char* Bd = Ad + 16384;
#pragma unroll
    for (int ks = 0; ks < 2; ++ks) {
      bf16x8 af[4], bfr[4];
#pragma unroll
      for (int mf = 0; mf < 4; ++mf) {
        int r = wr * 64 + mf * 16 + lr;
        int c = ks * 64 + lq * 16;
        af[mf] = *(const bf16x8*)(Ad + r * 128 + (c ^ ((r & 7) << 4)));
      }
#pragma unroll
      for (int nf = 0; nf < 4; ++nf) {
        int r = wc * 64 + nf * 16 + lr;
        int c = ks * 64 + lq * 16;
        bfr[nf] = *(const bf16x8*)(Bd + r * 128 + (c ^ ((r & 7) << 4)));
      }
      __builtin_amdgcn_s_setprio(1);
#pragma unroll
      for (int mf = 0; mf < 4; ++mf)
#pragma unroll
        for (int nf = 0; nf < 4; ++nf)
          acc[mf][nf] = __builtin_amdgcn_mfma_f32_16x16x32_bf16(af[mf], bfr[nf], acc[mf][nf], 0, 0, 0);
      __builtin_amdgcn_s_setprio(0);
    }
  }

  // bias add: C row m = M0 + wr*64 + mf*16 + lq*4 + r
#pragma unroll
  for (int mf = 0; mf < 4; ++mf) {
    f32x4 bv = *(const f32x4*)(bias + M0 + wr * 64 + mf * 16 + lq * 4);
#pragma unroll
    for (int nf = 0; nf < 4; ++nf) acc[mf][nf] += bv;
  }

  __syncthreads();  // all reads of smem done before reuse
  if (M0 < 1024) {
    // q/k: transposed store via LDS. Whole tile fits: Ct[128 n][136 m-stride]
    unsigned short* Ct = smem;
#pragma unroll
    for (int mf = 0; mf < 4; ++mf)
#pragma unroll
      for (int nf = 0; nf < 4; ++nf) {
        int n = wc * 64 + nf * 16 + lr;
        int m = wr * 64 + mf * 16 + lq * 4;
        ushort4 pk;
        pk.x = f2bf(acc[mf][nf].x); pk.y = f2bf(acc[mf][nf].y);
        pk.z = f2bf(acc[mf][nf].z); pk.w = f2bf(acc[mf][nf].w);
        *(ushort4*)(Ct + n * 136 + m) = pk;
      }
    __syncthreads();
    int n = tid >> 1, half = tid & 1;       // 128 rows x 2 half-rows of 64
    const unsigned short* src = Ct + n * 136 + half * 64;
    unsigned short* dst = qk_t + (N0 + n) * 1024 + M0 + half * 64;
#pragma unroll
    for (int ch = 0; ch < 8; ++ch)
      *(uint4*)(dst + ch * 8) = *(const uint4*)(src + ch * 8);
  } else {
    // v: natural layout, scalar stores (16 lanes -> 32B contiguous, L2 combines)
#pragma unroll
    for (int mf = 0; mf < 4; ++mf)
#pragma unroll
      for (int nf = 0; nf < 4; ++nf) {
        int m = M0 - 1024 + wr * 64 + mf * 16 + lq * 4;
        size_t n = N0 + wc * 64 + nf * 16 + lr;
#pragma unroll
        for (int r = 0; r < 4; ++r)
          v_nat[(size_t)(m + r) * NPIX + n] = f2bf(acc[mf][nf][r]);
      }
  }
}

// ------------- attention v2: one block per (h, fixed), 32x32x16 MFMA --------
// (R6/R8 version, unchanged)
template <int PHASE>
__global__ __launch_bounds__(512) void k_attn2(const unsigned short* __restrict__ qk_t,
                                               const unsigned short* __restrict__ v_nat,
                                               const float* __restrict__ x,
                                               float* __restrict__ out1,
                                               unsigned short* __restrict__ out_bt) {
  __shared__ unsigned short smem[32768];      // 64 KiB: K^T 32K | V 32K; later Obt
  unsigned short* Ks = smem;                  // K^T [256 j][64 c], XOR-swizzled
  unsigned short* Vs = smem + 16384;          // V   [64 d][256 j], XOR-swizzled
  const int tid = threadIdx.x;
  const int lane = tid & 63, wave = tid >> 6;
  const int l31 = lane & 31, hi = lane >> 5;
  const int fix = blockIdx.x, h = blockIdx.y;
  const size_t pixbase = (size_t)fix * 256;
  const int i0w = wave * 32;

  // stage K^T (cols 512 + h*64 of qk_t rows)
#pragma unroll
  for (int it = 0; it < 4; ++it) {
    int f = it * 512 + tid;
    int j = f >> 3, ch = f & 7;
    uint4 val = *(const uint4*)(qk_t + (pixbase + j) * 1024 + 512 + h * 64 + ch * 8);
    *(uint4*)((char*)Ks + j * 128 + ((ch * 16) ^ ((j & 7) << 4))) = val;
  }
  // stage V
#pragma unroll
  for (int it = 0; it < 4; ++it) {
    int f = it * 512 + tid;
    int d = f >> 5, c2 = f & 31;
    uint4 val = *(const uint4*)(v_nat + (size_t)(h * 64 + d) * NPIX + pixbase + c2 * 8);
    *(uint4*)((char*)Vs + d * 512 + ((c2 * 16) ^ ((d & 7) << 4))) = val;
  }
  // Q fragments (B-operand): lane(hi, i=l31) holds Q[c = ks*16 + hi*8 + e][i]
  bf16x8 qf[4];
  {
    const unsigned short* qp = qk_t + (pixbase + i0w + l31) * 1024 + h * 64 + hi * 8;
#pragma unroll
    for (int ks = 0; ks < 4; ++ks) qf[ks] = *(const bf16x8*)(qp + ks * 16);
  }
  __syncthreads();

  // QK^T
  f32x16 s[8] = {};
  const int swz = (l31 & 7) << 4;
  __builtin_amdgcn_s_setprio(1);
#pragma unroll
  for (int jt = 0; jt < 8; ++jt) {
    const char* kr = (const char*)Ks + (jt * 32 + l31) * 128;
#pragma unroll
    for (int ks = 0; ks < 4; ++ks) {
      bf16x8 kf = *(const bf16x8*)(kr + ((ks * 32 + hi * 16) ^ swz));
      s[jt] = __builtin_amdgcn_mfma_f32_32x32x16_bf16(kf, qf[ks], s[jt], 0, 0, 0);
    }
  }
  __builtin_amdgcn_s_setprio(0);

  // softmax over j (row i = l31; 128 values in-lane, partner half has the rest)
  float mx = -3.4e38f;
#pragma unroll
  for (int jt = 0; jt < 8; ++jt)
#pragma unroll
    for (int r = 0; r < 16; ++r) mx = fmaxf(mx, s[jt][r]);
  mx = fmaxf(mx, __shfl_xor(mx, 32, 64));
  float sum = 0.f;
#pragma unroll
  for (int jt = 0; jt < 8; ++jt)
#pragma unroll
    for (int r = 0; r < 16; ++r) {
      float p = __expf(s[jt][r] - mx);
      s[jt][r] = p; sum += p;
    }
  sum += __shfl_xor(sum, 32, 64);
  float inv = 1.f / sum;

  // P fragments (A-operand for PV), normalized, in-register regroup
  bf16x8 pf[16];
#pragma unroll
  for (int jt = 0; jt < 8; ++jt)
#pragma unroll
    for (int kb = 0; kb < 2; ++kb) {
      int kt = jt * 2 + kb;
      unsigned pA0 = cvtpk(s[jt][kb * 8 + 0] * inv, s[jt][kb * 8 + 1] * inv);
      unsigned pA1 = cvtpk(s[jt][kb * 8 + 2] * inv, s[jt][kb * 8 + 3] * inv);
      unsigned pB0 = cvtpk(s[jt][kb * 8 + 4] * inv, s[jt][kb * 8 + 5] * inv);
      unsigned pB1 = cvtpk(s[jt][kb * 8 + 6] * inv, s[jt][kb * 8 + 7] * inv);
      // half-0 sends its B-quad (needed by hi=1 targets); half-1 sends its A-quad
      unsigned s0 = hi ? pA0 : pB0;
      unsigned s1 = hi ? pA1 : pB1;
      unsigned r0 = (unsigned)__shfl_xor((int)s0, 32, 64);
      unsigned r1 = (unsigned)__shfl_xor((int)s1, 32, 64);
      union { unsigned u[4]; bf16x8 v; } pk_;
      pk_.u[0] = hi ? r0 : pA0;   // e0,e1 (from half-0, quad 2kb+hi)
      pk_.u[1] = hi ? r1 : pA1;   // e2,e3
      pk_.u[2] = hi ? pB0 : r0;   // e4,e5 (from half-1, quad 2kb+hi)
      pk_.u[3] = hi ? pB1 : r1;   // e6,e7
      pf[kt] = pk_.v;
    }

  // PV: O^T[i][d]
  f32x16 o[2] = {};
  __builtin_amdgcn_s_setprio(1);
#pragma unroll
  for (int dt = 0; dt < 2; ++dt) {
    const char* vr = (const char*)Vs + (dt * 32 + l31) * 512;
#pragma unroll
    for (int kt = 0; kt < 16; ++kt) {
      bf16x8 vf = *(const bf16x8*)(vr + ((kt * 32 + hi * 16) ^ swz));
      o[dt] = __builtin_amdgcn_mfma_f32_32x32x16_bf16(pf[kt], vf, o[dt], 0, 0, 0);
    }
  }
  __builtin_amdgcn_s_setprio(0);

  // epilogue: lane(hi, d=dt*32+l31) holds O^T[i = q*8 + hi*4 + m][d], reg 4q+m
  if (PHASE == 0) {
#pragma unroll
    for (int dt = 0; dt < 2; ++dt) {
      int c = h * 64 + dt * 32 + l31;
      float* ob = out1 + (size_t)c * NPIX + pixbase + i0w;
      const float* xb = x + (size_t)c * NPIX + pixbase + i0w;
#pragma unroll
      for (int q = 0; q < 4; ++q) {
        int ib = q * 8 + hi * 4;
        float4 xv = *(const float4*)(xb + ib);
        float4 vv;
        vv.x = o[dt][q * 4 + 0] + xv.x;
        vv.y = o[dt][q * 4 + 1] + xv.y;
        vv.z = o[dt][q * 4 + 2] + xv.z;
        vv.w = o[dt][q * 4 + 3] + xv.w;
        *(float4*)(ob + ib) = vv;
        o[dt][q * 4 + 0] = vv.x; o[dt][q * 4 + 1] = vv.y;
        o[dt][q * 4 + 2] = vv.z; o[dt][q * 4 + 3] = vv.w;
      }
    }
    __syncthreads();                       // K/V reads done -> overlay Obt
    unsigned short* Obt = smem;            // [256 i][72 d] (72 for 16B-aligned rows)
#pragma unroll
    for (int dt = 0; dt < 2; ++dt) {
      int d = dt * 32 + l31;
#pragma unroll
      for (int q = 0; q < 4; ++q)
#pragma unroll
        for (int m = 0; m < 4; ++m)
          Obt[(i0w + q * 8 + hi * 4 + m) * 72 + d] = f2bf(o[dt][q * 4 + m]);
    }
    __syncthreads();
    int row = tid >> 1, half = tid & 1;
    const unsigned short* src = Obt + row * 72 + half * 32;
    unsigned short* dst = out_bt + ((size_t)row * 256 + fix) * 512 + h * 64 + half * 32;
#pragma unroll
    for (int c4 = 0; c4 < 4; ++c4)
      *(uint4*)(dst + c4 * 8) = *(const uint4*)(src + c4 * 8);
  } else {
#pragma unroll
    for (int dt = 0; dt < 2; ++dt) {
      int c = h * 64 + dt * 32 + l31;
      unsigned short* ob = out_bt + (size_t)c * NPIX + pixbase + i0w;
#pragma unroll
      for (int q = 0; q < 4; ++q) {
        ushort4 pkv;
        pkv.x = f2bf(o[dt][q * 4 + 0]);
        pkv.y = f2bf(o[dt][q * 4 + 1]);
        pkv.z = f2bf(o[dt][q * 4 + 2]);
        pkv.w = f2bf(o[dt][q * 4 + 3]);
        *(ushort4*)(ob + q * 8 + hi * 4) = pkv;
      }
    }
  }
}

// --------- final: out[c][s][l] += colout_bt[c][l][s] (LDS transpose-add) ----
__global__ __launch_bounds__(256) void k_final(const unsigned short* __restrict__ colt,
                                               float* __restrict__ out) {
  __shared__ unsigned short Xs[64 * 68];
  int c = blockIdx.y;
  int lt = blockIdx.x & 3, st = blockIdx.x >> 2;
  int l0 = lt * 64, s0 = st * 64;
  int t = threadIdx.x;
  for (int rep = 0; rep < 4; ++rep) {
    int f = rep * 256 + t, li = f >> 4, jj = f & 15;
    ushort4 v = *(const ushort4*)(colt + (size_t)c * NPIX + (size_t)(l0 + li) * 256 + s0 + jj * 4);
    *(ushort4*)(Xs + li * 68 + jj * 4) = v;
  }
  __syncthreads();
  int si = t >> 2, q = t & 3;
  float* drow = out + (size_t)c * NPIX + (size_t)(s0 + si) * 256 + l0 + q * 16;
  for (int h4 = 0; h4 < 4; ++h4) {
    float4 a = *(float4*)(drow + h4 * 4);
    a.x += bf2f(Xs[(q * 16 + h4 * 4 + 0) * 68 + si]);
    a.y += bf2f(Xs[(q * 16 + h4 * 4 + 1) * 68 + si]);
    a.z += bf2f(Xs[(q * 16 + h4 * 4 + 2) * 68 + si]);
    a.w += bf2f(Xs[(q * 16 + h4 * 4 + 3) * 68 + si]);
    *(float4*)(drow + h4 * 4) = a;
  }
}

extern "C" void kernel_launch(void* const* d_in, const int* in_sizes, int n_in,
                              void* d_out, int out_size, void* d_ws, size_t ws_size,
                              hipStream_t stream) {
  const float* x  = (const float*)d_in[0];
  const float* Wr = (const float*)d_in[1];
  const float* br = (const float*)d_in[2];
  const float* Wc = (const float*)d_in[3];
  const float* bc = (const float*)d_in[4];
  float* out = (float*)d_out;
  char* ws = (char*)d_ws;
  unsigned short* qk_t  = (unsigned short*)(ws);                            // 128 MB [65536][1024]
  unsigned short* v_nat = (unsigned short*)(ws + 134217728);                // 64 MB  [512][65536]
  unsigned short* scr3  = (unsigned short*)(ws + 134217728 + 67108864);     // 64 MB  x^T / out1bt / colout
  unsigned short* Wrb   = (unsigned short*)(ws + 268435456);                // 1.5 MB
  unsigned short* Wcb   = (unsigned short*)(ws + 268435456 + 1572864);      // 1.5 MB

  k_cvt<<<768, 256, 0, stream>>>(Wr, Wrb, 196608);
  k_cvt<<<768, 256, 0, stream>>>(Wc, Wcb, 196608);
  k_cvt_transpose<<<dim3(1024, 8), 256, 0, stream>>>(x, scr3);              // scr3 = x^T bf16
  k_gemm<<<dim3(12, 512), 256, 0, stream>>>(Wrb, scr3, br, qk_t, v_nat);    // row QKV
  k_attn2<0><<<dim3(256, 8), 512, 0, stream>>>(qk_t, v_nat, x, out, scr3);  // out=out1, scr3=out1^T bf16
  k_gemm<<<dim3(12, 512), 256, 0, stream>>>(Wcb, scr3, bc, qk_t, v_nat);    // col QKV
  k_attn2<1><<<dim3(256, 8), 512, 0, stream>>>(qk_t, v_nat, nullptr, nullptr, scr3); // scr3=colout
  k_final<<<dim3(16, 512), 256, 0, stream>>>(scr3, out);                    // out += colout^T
}

// Round 10
// 606.121 us; speedup vs baseline: 4.1663x; 1.0168x over previous
//
#include <hip/hip_runtime.h>

typedef __bf16 bf16_t;
typedef __attribute__((ext_vector_type(8))) __bf16 bf16x8;
typedef __attribute__((ext_vector_type(4))) float f32x4;
typedef __attribute__((ext_vector_type(16))) float f32x16;

#define NH   8
#define DH   64
#define DD   512
#define NPIX 65536   // 256*256

__device__ __forceinline__ unsigned short f2bf(float f) {
  unsigned int u = __builtin_bit_cast(unsigned int, f);
  u += 0x7fffu + ((u >> 16) & 1u);
  return (unsigned short)(u >> 16);
}
__device__ __forceinline__ float bf2f(unsigned short b) {
  return __builtin_bit_cast(float, ((unsigned int)b) << 16);
}
__device__ __forceinline__ unsigned cvtpk(float a, float b) {
  unsigned r;
  asm("v_cvt_pk_bf16_f32 %0, %1, %2" : "=v"(r) : "v"(a), "v"(b));
  return r;
}

__device__ __forceinline__ void gload_lds16(const void* g, void* l) {
  __builtin_amdgcn_global_load_lds(
      (const __attribute__((address_space(1))) void*)(uintptr_t)g,
      (__attribute__((address_space(3))) void*)(uintptr_t)l, 16, 0, 0);
}

// ---------------- elementwise fp32 -> bf16 convert (weights) ----------------
__global__ __launch_bounds__(256) void k_cvt(const float* __restrict__ in,
                                             unsigned short* __restrict__ out, int n4) {
  int i = blockIdx.x * 256 + threadIdx.x;
  if (i >= n4) return;
  float4 v = ((const float4*)in)[i];
  ushort4 o; o.x = f2bf(v.x); o.y = f2bf(v.y); o.z = f2bf(v.z); o.w = f2bf(v.w);
  ((ushort4*)out)[i] = o;
}

// ------------- x [512][65536] f32 -> x^T [65536][512] bf16 ------------------
__global__ __launch_bounds__(256) void k_cvt_transpose(const float* __restrict__ x,
                                                       unsigned short* __restrict__ xt) {
  __shared__ unsigned short Xs[64 * 68];
  int p0 = blockIdx.x * 64, c0 = blockIdx.y * 64;
  int t = threadIdx.x;
  for (int rep = 0; rep < 4; ++rep) {
    int f = rep * 256 + t, i = f >> 4, jj = f & 15;
    float4 v = *(const float4*)(x + (size_t)(c0 + i) * NPIX + p0 + jj * 4);
    ushort4 o; o.x = f2bf(v.x); o.y = f2bf(v.y); o.z = f2bf(v.z); o.w = f2bf(v.w);
    *(ushort4*)(Xs + i * 68 + jj * 4) = o;
  }
  __syncthreads();
  int j = t >> 2, q = t & 3;
  unsigned short* dst = xt + (size_t)(p0 + j) * DD + c0 + q * 16;
  for (int h2 = 0; h2 < 2; ++h2) {
    union { unsigned short u[8]; uint4 v; } pk;
    for (int cc = 0; cc < 8; ++cc) pk.u[cc] = Xs[(q * 16 + h2 * 8 + cc) * 68 + j];
    *(uint4*)(dst + h2 * 8) = pk.v;
  }
}

// ---------------- GEMM: C[1536][65536] = W[1536][512] @ X + b ---------------
// 128x128 tile, BK=64, 4 waves, DOUBLE-buffered 64 KiB LDS, 2 blocks/CU
// (launch_bounds(256,2) -> VGPR cap 256, no spill). Prefetch of tile t+1 is
// issued BEFORE computing tile t: by the trailing vmcnt(0) the loads had the
// whole compute phase to land; 2 co-resident blocks de-phase the stalls.
__global__ __launch_bounds__(256, 2) void k_gemm(const unsigned short* __restrict__ A,
                                                 const unsigned short* __restrict__ Bt,
                                                 const float* __restrict__ bias,
                                                 unsigned short* __restrict__ qk_t,
                                                 unsigned short* __restrict__ v_nat) {
  __shared__ unsigned short smem[32768];  // 64 KiB: 2 bufs x (A 128x64 | B 128x64)
  int tid = threadIdx.x, lane = tid & 63, wave = tid >> 6;
  int lr = lane & 15, lq = lane >> 4;
  // T1: bijective XCD swizzle over 6144 blocks (6144 % 8 == 0)
  int bid = blockIdx.y * 12 + blockIdx.x;
  int lid = (bid & 7) * 768 + (bid >> 3);
  int M0 = (lid % 12) * 128;
  size_t N0 = (size_t)(lid / 12) * 128;
  int wr = wave >> 1, wc = wave & 1;   // 2 x 2 wave grid; wave tile 64x64
  f32x4 acc[4][4] = {};

  const unsigned short* Abase = A + (size_t)M0 * 512;
  const unsigned short* Bbase = Bt + N0 * 512;

  // stage tile kt into buf b. LDS linear [128 rows][64 cols] per matrix;
  // T2: source chunk pre-swizzled so reads XOR ((row&7)<<4) conflict-free.
  auto STAGE = [&](int b, int kt) {
#pragma unroll
    for (int it = 0; it < 4; ++it) {
      int f = it * 256 + tid;          // 0..1023: row=f>>3, chunk=f&7
      int row = f >> 3;
      int cc = (f & 7) ^ (row & 7);
      const unsigned short* ga = Abase + (size_t)row * 512 + kt * 64 + cc * 8;
      gload_lds16(ga, smem + b * 16384 + f * 8);
      const unsigned short* gb = Bbase + (size_t)row * 512 + kt * 64 + cc * 8;
      gload_lds16(gb, smem + b * 16384 + 8192 + f * 8);
    }
  };

  STAGE(0, 0);
  asm volatile("s_waitcnt vmcnt(0)" ::: "memory");
  __syncthreads();
  int cur = 0;
  for (int kt = 0; kt < 8; ++kt) {
    if (kt < 7) STAGE(cur ^ 1, kt + 1);     // prefetch next tile
    const char* Ad = (const char*)smem + cur * 32768;
    const char* Bd = Ad + 16384;
#pragma unroll
    for (int ks = 0; ks < 2; ++ks) {
      bf16x8 af[4], bfr[4];
#pragma unroll
      for (int mf = 0; mf < 4; ++mf) {
        int r = wr * 64 + mf * 16 + lr;
        int c = ks * 64 + lq * 16;
        af[mf] = *(const bf16x8*)(Ad + r * 128 + (c ^ ((r & 7) << 4)));
      }
#pragma unroll
      for (int nf = 0; nf < 4; ++nf) {
        int r = wc * 64 + nf * 16 + lr;
        int c = ks * 64 + lq * 16;
        bfr[nf] = *(const bf16x8*)(Bd + r * 128 + (c ^ ((r & 7) << 4)));
      }
      __builtin_amdgcn_s_setprio(1);
#pragma unroll
      for (int mf = 0; mf < 4; ++mf)
#pragma unroll
        for (int nf = 0; nf < 4; ++nf)
          acc[mf][nf] = __builtin_amdgcn_mfma_f32_16x16x32_bf16(af[mf], bfr[nf], acc[mf][nf], 0, 0, 0);
      __builtin_amdgcn_s_setprio(0);
    }
    asm volatile("s_waitcnt vmcnt(0)" ::: "memory");  // next tile landed
    __syncthreads();
    cur ^= 1;
  }

  // bias add: C row m = M0 + wr*64 + mf*16 + lq*4 + r
#pragma unroll
  for (int mf = 0; mf < 4; ++mf) {
    f32x4 bv = *(const f32x4*)(bias + M0 + wr * 64 + mf * 16 + lq * 4);
#pragma unroll
    for (int nf = 0; nf < 4; ++nf) acc[mf][nf] += bv;
  }

  if (M0 < 1024) {
    // q/k: transposed store via LDS. Whole tile: Ct[128 n][136 m-stride]
    unsigned short* Ct = smem;
#pragma unroll
    for (int mf = 0; mf < 4; ++mf)
#pragma unroll
      for (int nf = 0; nf < 4; ++nf) {
        int n = wc * 64 + nf * 16 + lr;
        int m = wr * 64 + mf * 16 + lq * 4;
        ushort4 pk;
        pk.x = f2bf(acc[mf][nf].x); pk.y = f2bf(acc[mf][nf].y);
        pk.z = f2bf(acc[mf][nf].z); pk.w = f2bf(acc[mf][nf].w);
        *(ushort4*)(Ct + n * 136 + m) = pk;
      }
    __syncthreads();
    int n = tid >> 1, half = tid & 1;       // 128 rows x 2 half-rows of 64
    const unsigned short* src = Ct + n * 136 + half * 64;
    unsigned short* dst = qk_t + (N0 + n) * 1024 + M0 + half * 64;
#pragma unroll
    for (int ch = 0; ch < 8; ++ch)
      *(uint4*)(dst + ch * 8) = *(const uint4*)(src + ch * 8);
  } else {
    // v: natural layout, scalar stores (16 lanes -> 32B contiguous, L2 combines)
#pragma unroll
    for (int mf = 0; mf < 4; ++mf)
#pragma unroll
      for (int nf = 0; nf < 4; ++nf) {
        int m = M0 - 1024 + wr * 64 + mf * 16 + lq * 4;
        size_t n = N0 + wc * 64 + nf * 16 + lr;
#pragma unroll
        for (int r = 0; r < 4; ++r)
          v_nat[(size_t)(m + r) * NPIX + n] = f2bf(acc[mf][nf][r]);
      }
  }
}

// ------------- attention v2: one block per (h, fixed), 32x32x16 MFMA --------
// PHASE 0, NAT=1: out1 written as bf16 NATURAL [c][p] (out1nat) + bf16
//                 transposed (out_bt). No fp32 out1 traffic.
// PHASE 0, NAT=0: legacy path (fp32 out1 into d_out) for small-ws fallback.
// PHASE 1: colout_bt[c][fix*256+i] = bf16(O)
template <int PHASE, int NAT>
__global__ __launch_bounds__(512) void k_attn2(const unsigned short* __restrict__ qk_t,
                                               const unsigned short* __restrict__ v_nat,
                                               const float* __restrict__ x,
                                               float* __restrict__ out1,
                                               unsigned short* __restrict__ out1nat,
                                               unsigned short* __restrict__ out_bt) {
  __shared__ unsigned short smem[32768];      // 64 KiB: K^T 32K | V 32K; later Obt
  unsigned short* Ks = smem;                  // K^T [256 j][64 c], XOR-swizzled
  unsigned short* Vs = smem + 16384;          // V   [64 d][256 j], XOR-swizzled
  const int tid = threadIdx.x;
  const int lane = tid & 63, wave = tid >> 6;
  const int l31 = lane & 31, hi = lane >> 5;
  const int fix = blockIdx.x, h = blockIdx.y;
  const size_t pixbase = (size_t)fix * 256;
  const int i0w = wave * 32;

  // stage K^T (cols 512 + h*64 of qk_t rows)
#pragma unroll
  for (int it = 0; it < 4; ++it) {
    int f = it * 512 + tid;
    int j = f >> 3, ch = f & 7;
    uint4 val = *(const uint4*)(qk_t + (pixbase + j) * 1024 + 512 + h * 64 + ch * 8);
    *(uint4*)((char*)Ks + j * 128 + ((ch * 16) ^ ((j & 7) << 4))) = val;
  }
  // stage V
#pragma unroll
  for (int it = 0; it < 4; ++it) {
    int f = it * 512 + tid;
    int d = f >> 5, c2 = f & 31;
    uint4 val = *(const uint4*)(v_nat + (size_t)(h * 64 + d) * NPIX + pixbase + c2 * 8);
    *(uint4*)((char*)Vs + d * 512 + ((c2 * 16) ^ ((d & 7) << 4))) = val;
  }
  // Q fragments (B-operand): lane(hi, i=l31) holds Q[c = ks*16 + hi*8 + e][i]
  bf16x8 qf[4];
  {
    const unsigned short* qp = qk_t + (pixbase + i0w + l31) * 1024 + h * 64 + hi * 8;
#pragma unroll
    for (int ks = 0; ks < 4; ++ks) qf[ks] = *(const bf16x8*)(qp + ks * 16);
  }
  __syncthreads();

  // QK^T
  f32x16 s[8] = {};
  const int swz = (l31 & 7) << 4;
  __builtin_amdgcn_s_setprio(1);
#pragma unroll
  for (int jt = 0; jt < 8; ++jt) {
    const char* kr = (const char*)Ks + (jt * 32 + l31) * 128;
#pragma unroll
    for (int ks = 0; ks < 4; ++ks) {
      bf16x8 kf = *(const bf16x8*)(kr + ((ks * 32 + hi * 16) ^ swz));
      s[jt] = __builtin_amdgcn_mfma_f32_32x32x16_bf16(kf, qf[ks], s[jt], 0, 0, 0);
    }
  }
  __builtin_amdgcn_s_setprio(0);

  // softmax over j
  float mx = -3.4e38f;
#pragma unroll
  for (int jt = 0; jt < 8; ++jt)
#pragma unroll
    for (int r = 0; r < 16; ++r) mx = fmaxf(mx, s[jt][r]);
  mx = fmaxf(mx, __shfl_xor(mx, 32, 64));
  float sum = 0.f;
#pragma unroll
  for (int jt = 0; jt < 8; ++jt)
#pragma unroll
    for (int r = 0; r < 16; ++r) {
      float p = __expf(s[jt][r] - mx);
      s[jt][r] = p; sum += p;
    }
  sum += __shfl_xor(sum, 32, 64);
  float inv = 1.f / sum;

  // P fragments (A-operand for PV), normalized, in-register regroup
  bf16x8 pf[16];
#pragma unroll
  for (int jt = 0; jt < 8; ++jt)
#pragma unroll
    for (int kb = 0; kb < 2; ++kb) {
      int kt = jt * 2 + kb;
      unsigned pA0 = cvtpk(s[jt][kb * 8 + 0] * inv, s[jt][kb * 8 + 1] * inv);
      unsigned pA1 = cvtpk(s[jt][kb * 8 + 2] * inv, s[jt][kb * 8 + 3] * inv);
      unsigned pB0 = cvtpk(s[jt][kb * 8 + 4] * inv, s[jt][kb * 8 + 5] * inv);
      unsigned pB1 = cvtpk(s[jt][kb * 8 + 6] * inv, s[jt][kb * 8 + 7] * inv);
      unsigned s0 = hi ? pA0 : pB0;
      unsigned s1 = hi ? pA1 : pB1;
      unsigned r0 = (unsigned)__shfl_xor((int)s0, 32, 64);
      unsigned r1 = (unsigned)__shfl_xor((int)s1, 32, 64);
      union { unsigned u[4]; bf16x8 v; } pk_;
      pk_.u[0] = hi ? r0 : pA0;
      pk_.u[1] = hi ? r1 : pA1;
      pk_.u[2] = hi ? pB0 : r0;
      pk_.u[3] = hi ? pB1 : r1;
      pf[kt] = pk_.v;
    }

  // PV: O^T[i][d]
  f32x16 o[2] = {};
  __builtin_amdgcn_s_setprio(1);
#pragma unroll
  for (int dt = 0; dt < 2; ++dt) {
    const char* vr = (const char*)Vs + (dt * 32 + l31) * 512;
#pragma unroll
    for (int kt = 0; kt < 16; ++kt) {
      bf16x8 vf = *(const bf16x8*)(vr + ((kt * 32 + hi * 16) ^ swz));
      o[dt] = __builtin_amdgcn_mfma_f32_32x32x16_bf16(pf[kt], vf, o[dt], 0, 0, 0);
    }
  }
  __builtin_amdgcn_s_setprio(0);

  // epilogue: lane(hi, d=dt*32+l31) holds O^T[i = q*8 + hi*4 + m][d], reg 4q+m
  if (PHASE == 0) {
#pragma unroll
    for (int dt = 0; dt < 2; ++dt) {
      int c = h * 64 + dt * 32 + l31;
      const float* xb = x + (size_t)c * NPIX + pixbase + i0w;
#pragma unroll
      for (int q = 0; q < 4; ++q) {
        int ib = q * 8 + hi * 4;
        float4 xv = *(const float4*)(xb + ib);
        float4 vv;
        vv.x = o[dt][q * 4 + 0] + xv.x;
        vv.y = o[dt][q * 4 + 1] + xv.y;
        vv.z = o[dt][q * 4 + 2] + xv.z;
        vv.w = o[dt][q * 4 + 3] + xv.w;
        if (NAT) {
          ushort4 pk;
          pk.x = f2bf(vv.x); pk.y = f2bf(vv.y); pk.z = f2bf(vv.z); pk.w = f2bf(vv.w);
          *(ushort4*)(out1nat + (size_t)c * NPIX + pixbase + i0w + ib) = pk;
        } else {
          *(float4*)(out1 + (size_t)c * NPIX + pixbase + i0w + ib) = vv;
        }
        o[dt][q * 4 + 0] = vv.x; o[dt][q * 4 + 1] = vv.y;
        o[dt][q * 4 + 2] = vv.z; o[dt][q * 4 + 3] = vv.w;
      }
    }
    __syncthreads();                       // K/V reads done -> overlay Obt
    unsigned short* Obt = smem;            // [256 i][72 d]
#pragma unroll
    for (int dt = 0; dt < 2; ++dt) {
      int d = dt * 32 + l31;
#pragma unroll
      for (int q = 0; q < 4; ++q)
#pragma unroll
        for (int m = 0; m < 4; ++m)
          Obt[(i0w + q * 8 + hi * 4 + m) * 72 + d] = f2bf(o[dt][q * 4 + m]);
    }
    __syncthreads();
    int row = tid >> 1, half = tid & 1;
    const unsigned short* src = Obt + row * 72 + half * 32;
    unsigned short* dst = out_bt + ((size_t)row * 256 + fix) * 512 + h * 64 + half * 32;
#pragma unroll
    for (int c4 = 0; c4 < 4; ++c4)
      *(uint4*)(dst + c4 * 8) = *(const uint4*)(src + c4 * 8);
  } else {
#pragma unroll
    for (int dt = 0; dt < 2; ++dt) {
      int c = h * 64 + dt * 32 + l31;
      unsigned short* ob = out_bt + (size_t)c * NPIX + pixbase + i0w;
#pragma unroll
      for (int q = 0; q < 4; ++q) {
        ushort4 pkv;
        pkv.x = f2bf(o[dt][q * 4 + 0]);
        pkv.y = f2bf(o[dt][q * 4 + 1]);
        pkv.z = f2bf(o[dt][q * 4 + 2]);
        pkv.w = f2bf(o[dt][q * 4 + 3]);
        *(ushort4*)(ob + q * 8 + hi * 4) = pkv;
      }
    }
  }
}

// --------- final: out[c][s][l] = out1 + colout_bt[c][l][s]^T ---------------
// NAT=1: out1 read as bf16 natural (out1nat); NAT=0: RMW fp32 out (legacy).
template <int NAT>
__global__ __launch_bounds__(256) void k_final(const unsigned short* __restrict__ colt,
                                               const unsigned short* __restrict__ out1nat,
                                               float* __restrict__ out) {
  __shared__ unsigned short Xs[64 * 68];
  int c = blockIdx.y;
  int lt = blockIdx.x & 3, st = blockIdx.x >> 2;
  int l0 = lt * 64, s0 = st * 64;
  int t = threadIdx.x;
  for (int rep = 0; rep < 4; ++rep) {
    int f = rep * 256 + t, li = f >> 4, jj = f & 15;
    ushort4 v = *(const ushort4*)(colt + (size_t)c * NPIX + (size_t)(l0 + li) * 256 + s0 + jj * 4);
    *(ushort4*)(Xs + li * 68 + jj * 4) = v;
  }
  __syncthreads();
  int si = t >> 2, q = t & 3;
  size_t rowoff = (size_t)c * NPIX + (size_t)(s0 + si) * 256 + l0 + q * 16;
  float* drow = out + rowoff;
  for (int h4 = 0; h4 < 4; ++h4) {
    float4 a;
    if (NAT) {
      ushort4 nv = *(const ushort4*)(out1nat + rowoff + h4 * 4);
      a.x = bf2f(nv.x); a.y = bf2f(nv.y); a.z = bf2f(nv.z); a.w = bf2f(nv.w);
    } else {
      a = *(float4*)(drow + h4 * 4);
    }
    a.x += bf2f(Xs[(q * 16 + h4 * 4 + 0) * 68 + si]);
    a.y += bf2f(Xs[(q * 16 + h4 * 4 + 1) * 68 + si]);
    a.z += bf2f(Xs[(q * 16 + h4 * 4 + 2) * 68 + si]);
    a.w += bf2f(Xs[(q * 16 + h4 * 4 + 3) * 68 + si]);
    *(float4*)(drow + h4 * 4) = a;
  }
}

extern "C" void kernel_launch(void* const* d_in, const int* in_sizes, int n_in,
                              void* d_out, int out_size, void* d_ws, size_t ws_size,
                              hipStream_t stream) {
  const float* x  = (const float*)d_in[0];
  const float* Wr = (const float*)d_in[1];
  const float* br = (const float*)d_in[2];
  const float* Wc = (const float*)d_in[3];
  const float* bc = (const float*)d_in[4];
  float* out = (float*)d_out;
  char* ws = (char*)d_ws;
  unsigned short* qk_t   = (unsigned short*)(ws);                        // 128 MB
  unsigned short* v_nat  = (unsigned short*)(ws + 134217728);            // 64 MB
  unsigned short* scr3   = (unsigned short*)(ws + 201326592);            // 64 MB
  unsigned short* Wrb    = (unsigned short*)(ws + 268435456);            // 1.5 MB
  unsigned short* Wcb    = (unsigned short*)(ws + 270008320);            // 1.5 MB
  unsigned short* o1nat  = (unsigned short*)(ws + 271581184);            // 64 MB (if fits)
  const bool nat = ws_size >= 338690048ull;   // 271581184 + 67108864

  k_cvt<<<768, 256, 0, stream>>>(Wr, Wrb, 196608);
  k_cvt<<<768, 256, 0, stream>>>(Wc, Wcb, 196608);
  k_cvt_transpose<<<dim3(1024, 8), 256, 0, stream>>>(x, scr3);           // scr3 = x^T bf16
  k_gemm<<<dim3(12, 512), 256, 0, stream>>>(Wrb, scr3, br, qk_t, v_nat); // row QKV
  if (nat)
    k_attn2<0, 1><<<dim3(256, 8), 512, 0, stream>>>(qk_t, v_nat, x, nullptr, o1nat, scr3);
  else
    k_attn2<0, 0><<<dim3(256, 8), 512, 0, stream>>>(qk_t, v_nat, x, out, nullptr, scr3);
  k_gemm<<<dim3(12, 512), 256, 0, stream>>>(Wcb, scr3, bc, qk_t, v_nat); // col QKV
  k_attn2<1, 0><<<dim3(256, 8), 512, 0, stream>>>(qk_t, v_nat, nullptr, nullptr, nullptr, scr3);
  if (nat)
    k_final<1><<<dim3(16, 512), 256, 0, stream>>>(scr3, o1nat, out);
  else
    k_final<0><<<dim3(16, 512), 256, 0, stream>>>(scr3, nullptr, out);
}

// Round 11
// 505.712 us; speedup vs baseline: 4.9936x; 1.1986x over previous
//
#include <hip/hip_runtime.h>

typedef __bf16 bf16_t;
typedef __attribute__((ext_vector_type(8))) __bf16 bf16x8;
typedef __attribute__((ext_vector_type(4))) float f32x4;
typedef __attribute__((ext_vector_type(16))) float f32x16;

#define NH   8
#define DH   64
#define DD   512
#define NPIX 65536   // 256*256

__device__ __forceinline__ unsigned short f2bf(float f) {
  unsigned int u = __builtin_bit_cast(unsigned int, f);
  u += 0x7fffu + ((u >> 16) & 1u);
  return (unsigned short)(u >> 16);
}
__device__ __forceinline__ float bf2f(unsigned short b) {
  return __builtin_bit_cast(float, ((unsigned int)b) << 16);
}
__device__ __forceinline__ unsigned cvtpk(float a, float b) {
  unsigned r;
  asm("v_cvt_pk_bf16_f32 %0, %1, %2" : "=v"(r) : "v"(a), "v"(b));
  return r;
}

__device__ __forceinline__ void gload_lds16(const void* g, void* l) {
  __builtin_amdgcn_global_load_lds(
      (const __attribute__((address_space(1))) void*)(uintptr_t)g,
      (__attribute__((address_space(3))) void*)(uintptr_t)l, 16, 0, 0);
}

// ---------------- elementwise fp32 -> bf16 convert (weights) ----------------
__global__ __launch_bounds__(256) void k_cvt(const float* __restrict__ in,
                                             unsigned short* __restrict__ out, int n4) {
  int i = blockIdx.x * 256 + threadIdx.x;
  if (i >= n4) return;
  float4 v = ((const float4*)in)[i];
  ushort4 o; o.x = f2bf(v.x); o.y = f2bf(v.y); o.z = f2bf(v.z); o.w = f2bf(v.w);
  ((ushort4*)out)[i] = o;
}

// ------------- x [512][65536] f32 -> x^T [65536][512] bf16 ------------------
__global__ __launch_bounds__(256) void k_cvt_transpose(const float* __restrict__ x,
                                                       unsigned short* __restrict__ xt) {
  __shared__ unsigned short Xs[64 * 68];
  int p0 = blockIdx.x * 64, c0 = blockIdx.y * 64;
  int t = threadIdx.x;
  for (int rep = 0; rep < 4; ++rep) {
    int f = rep * 256 + t, i = f >> 4, jj = f & 15;
    float4 v = *(const float4*)(x + (size_t)(c0 + i) * NPIX + p0 + jj * 4);
    ushort4 o; o.x = f2bf(v.x); o.y = f2bf(v.y); o.z = f2bf(v.z); o.w = f2bf(v.w);
    *(ushort4*)(Xs + i * 68 + jj * 4) = o;
  }
  __syncthreads();
  int j = t >> 2, q = t & 3;
  unsigned short* dst = xt + (size_t)(p0 + j) * DD + c0 + q * 16;
  for (int h2 = 0; h2 < 2; ++h2) {
    union { unsigned short u[8]; uint4 v; } pk;
    for (int cc = 0; cc < 8; ++cc) pk.u[cc] = Xs[(q * 16 + h2 * 8 + cc) * 68 + j];
    *(uint4*)(dst + h2 * 8) = pk.v;
  }
}

// -------- FUSED QKV-projection + axial attention, one block per (h,fix) -----
// GEMM phase: C[192][256] = W_h[192x512] @ panel[fix*256..+256, 512]^T + bias.
//   8 waves (2m x 4n), wave tile 96x64, mfma_32x32x16, double-buffered LDS
//   staging (2 x 56 KiB). W rows gathered: global row (r>>6)*512 + h*64 + (r&63).
// Epilogue: q,k stored TRANSPOSED ([p][c], XOR-swizzled), v natural ([d][j],
//   XOR-swizzled) into LDS (96 KiB, overlays staging after final barrier).
// Attention phase: verbatim attn2 body (QK^T -> in-lane softmax -> in-register
//   cvt_pk/shfl P-regroup -> PV), reading K/V/Q from the LDS qkv.
// IS_COL=0: outnat = bf16(x + O) [c][p], outbt = transposed copy [p][c]
// IS_COL=1: outnat = bf16(O) [c][fix*256+i]
template <int IS_COL>
__global__ __launch_bounds__(512, 2) void k_fused(const unsigned short* __restrict__ panel,
                                                  const unsigned short* __restrict__ Wb,
                                                  const float* __restrict__ bias,
                                                  const float* __restrict__ x,
                                                  unsigned short* __restrict__ outnat,
                                                  unsigned short* __restrict__ outbt) {
  __shared__ unsigned short smem[57344];   // 112 KiB
  const int tid = threadIdx.x, lane = tid & 63, wave = tid >> 6;
  const int l31 = lane & 31, hi = lane >> 5;
  // chunked-XCD remap: 2048 blocks; the 8 h-siblings of one fix share a B-panel
  // and land on one XCD (lid = fix*8 + h).
  int bid = blockIdx.y * 8 + blockIdx.x;
  int lid = (bid & 7) * 256 + (bid >> 3);
  const int h = lid & 7, fix = lid >> 3;
  const size_t pixbase = (size_t)fix * 256;
  const int wm = wave >> 2, wn = wave & 3;   // 2 x 4 wave grid
  const int i0w = wave * 32;

  const unsigned short* Pbase = panel + pixbase * 512;

  // stage K-tile kt into buf b: A = W_h [192][64], B = panel [256][64].
  // T2: source chunk pre-swizzled so ds_reads XOR ((row&7)<<4) conflict-free.
  auto STAGE = [&](int b, int kt) {
    unsigned short* Ab = smem + b * 28672;
    unsigned short* Bb = Ab + 12288;
#pragma unroll
    for (int it = 0; it < 3; ++it) {       // A: 192 rows x 8 chunks
      int f = it * 512 + tid;
      int row = f >> 3;
      int cc = (f & 7) ^ (row & 7);
      int grow = (row >> 6) * 512 + h * 64 + (row & 63);
      gload_lds16(Wb + (size_t)grow * 512 + kt * 64 + cc * 8, Ab + f * 8);
    }
#pragma unroll
    for (int it = 0; it < 4; ++it) {       // B: 256 rows x 8 chunks
      int f = it * 512 + tid;
      int row = f >> 3;
      int cc = (f & 7) ^ (row & 7);
      gload_lds16(Pbase + (size_t)row * 512 + kt * 64 + cc * 8, Bb + f * 8);
    }
  };

  f32x16 acc[3][2] = {};
  STAGE(0, 0);
  asm volatile("s_waitcnt vmcnt(0)" ::: "memory");
  __syncthreads();
  int cur = 0;
  for (int kt = 0; kt < 8; ++kt) {
    if (kt < 7) STAGE(cur ^ 1, kt + 1);    // prefetch next tile
    const char* Ad = (const char*)smem + cur * 57344;
    const char* Bd = Ad + 24576;
#pragma unroll
    for (int ks = 0; ks < 4; ++ks) {
      bf16x8 afr[3], bfr[2];
#pragma unroll
      for (int mt = 0; mt < 3; ++mt) {
        int r = wm * 96 + mt * 32 + l31;
        afr[mt] = *(const bf16x8*)(Ad + r * 128 + ((ks * 32 + hi * 16) ^ ((r & 7) << 4)));
      }
#pragma unroll
      for (int nt = 0; nt < 2; ++nt) {
        int r = wn * 64 + nt * 32 + l31;
        bfr[nt] = *(const bf16x8*)(Bd + r * 128 + ((ks * 32 + hi * 16) ^ ((r & 7) << 4)));
      }
      __builtin_amdgcn_s_setprio(1);
#pragma unroll
      for (int mt = 0; mt < 3; ++mt)
#pragma unroll
        for (int nt = 0; nt < 2; ++nt)
          acc[mt][nt] = __builtin_amdgcn_mfma_f32_32x32x16_bf16(afr[mt], bfr[nt], acc[mt][nt], 0, 0, 0);
      __builtin_amdgcn_s_setprio(0);
    }
    asm volatile("s_waitcnt vmcnt(0)" ::: "memory");
    __syncthreads();
    cur ^= 1;
  }
  // all LDS reads of staging done (loop-end barrier) -> overlay qkv
  unsigned short* Qt = smem;               // [256 p][64 c] swz, 32 KiB
  unsigned short* Kt = smem + 16384;       // [256 j][64 c] swz, 32 KiB
  unsigned short* Vn = smem + 32768;       // [64 d][256 j] swz, 32 KiB
  // C row = wm*96 + mt*32 + 8q + 4hi + j (j<4), col = wn*64 + nt*32 + l31
#pragma unroll
  for (int mt = 0; mt < 3; ++mt) {
    int rb = wm * 96 + mt * 32 + 4 * hi;
#pragma unroll
    for (int q = 0; q < 4; ++q) {
      int crow = rb + 8 * q;               // strip of 4 rows
      int sel = crow >> 6, r64 = crow & 63;
      f32x4 bv = *(const f32x4*)(bias + sel * 512 + h * 64 + r64);
#pragma unroll
      for (int nt = 0; nt < 2; ++nt) {
        int col = wn * 64 + nt * 32 + l31;
        float v0 = acc[mt][nt][q * 4 + 0] + bv.x;
        float v1 = acc[mt][nt][q * 4 + 1] + bv.y;
        float v2 = acc[mt][nt][q * 4 + 2] + bv.z;
        float v3 = acc[mt][nt][q * 4 + 3] + bv.w;
        if (sel < 2) {                     // q,k -> transposed [p][c]
          ushort4 pk;
          pk.x = f2bf(v0); pk.y = f2bf(v1); pk.z = f2bf(v2); pk.w = f2bf(v3);
          char* base = (char*)(sel ? Kt : Qt);
          *(ushort4*)(base + col * 128 + ((r64 * 2) ^ ((col & 7) << 4))) = pk;
        } else {                           // v -> natural [d][j]
          char* base = (char*)Vn;
          *(unsigned short*)(base + (r64 + 0) * 512 + ((col * 2) ^ (((r64 + 0) & 7) << 4))) = f2bf(v0);
          *(unsigned short*)(base + (r64 + 1) * 512 + ((col * 2) ^ (((r64 + 1) & 7) << 4))) = f2bf(v1);
          *(unsigned short*)(base + (r64 + 2) * 512 + ((col * 2) ^ (((r64 + 2) & 7) << 4))) = f2bf(v2);
          *(unsigned short*)(base + (r64 + 3) * 512 + ((col * 2) ^ (((r64 + 3) & 7) << 4))) = f2bf(v3);
        }
      }
    }
  }
  __syncthreads();

  // ---------------- attention phase (attn2 body) ----------------
  const int swz = (l31 & 7) << 4;
  bf16x8 qf[4];
  {
    const char* qrow = (const char*)Qt + (i0w + l31) * 128;
#pragma unroll
    for (int ks = 0; ks < 4; ++ks)
      qf[ks] = *(const bf16x8*)(qrow + ((ks * 32 + hi * 16) ^ swz));
  }

  // QK^T: S^T[j][i], j over 8 jt tiles, i = l31 (+ wave's 32-query window)
  f32x16 s[8] = {};
  __builtin_amdgcn_s_setprio(1);
#pragma unroll
  for (int jt = 0; jt < 8; ++jt) {
    const char* kr = (const char*)Kt + (jt * 32 + l31) * 128;
#pragma unroll
    for (int ks = 0; ks < 4; ++ks) {
      bf16x8 kf = *(const bf16x8*)(kr + ((ks * 32 + hi * 16) ^ swz));
      s[jt] = __builtin_amdgcn_mfma_f32_32x32x16_bf16(kf, qf[ks], s[jt], 0, 0, 0);
    }
  }
  __builtin_amdgcn_s_setprio(0);

  // softmax over j (128 in-lane values; partner half has the other 128)
  float mx = -3.4e38f;
#pragma unroll
  for (int jt = 0; jt < 8; ++jt)
#pragma unroll
    for (int r = 0; r < 16; ++r) mx = fmaxf(mx, s[jt][r]);
  mx = fmaxf(mx, __shfl_xor(mx, 32, 64));
  float sum = 0.f;
#pragma unroll
  for (int jt = 0; jt < 8; ++jt)
#pragma unroll
    for (int r = 0; r < 16; ++r) {
      float p = __expf(s[jt][r] - mx);
      s[jt][r] = p; sum += p;
    }
  sum += __shfl_xor(sum, 32, 64);
  float inv = 1.f / sum;

  // P fragments (A-operand for PV), normalized, in-register regroup
  bf16x8 pf[16];
#pragma unroll
  for (int jt = 0; jt < 8; ++jt)
#pragma unroll
    for (int kb = 0; kb < 2; ++kb) {
      int kt2 = jt * 2 + kb;
      unsigned pA0 = cvtpk(s[jt][kb * 8 + 0] * inv, s[jt][kb * 8 + 1] * inv);
      unsigned pA1 = cvtpk(s[jt][kb * 8 + 2] * inv, s[jt][kb * 8 + 3] * inv);
      unsigned pB0 = cvtpk(s[jt][kb * 8 + 4] * inv, s[jt][kb * 8 + 5] * inv);
      unsigned pB1 = cvtpk(s[jt][kb * 8 + 6] * inv, s[jt][kb * 8 + 7] * inv);
      unsigned s0 = hi ? pA0 : pB0;
      unsigned s1 = hi ? pA1 : pB1;
      unsigned r0 = (unsigned)__shfl_xor((int)s0, 32, 64);
      unsigned r1 = (unsigned)__shfl_xor((int)s1, 32, 64);
      union { unsigned u[4]; bf16x8 v; } pk_;
      pk_.u[0] = hi ? r0 : pA0;
      pk_.u[1] = hi ? r1 : pA1;
      pk_.u[2] = hi ? pB0 : r0;
      pk_.u[3] = hi ? pB1 : r1;
      pf[kt2] = pk_.v;
    }

  // PV: O^T[i][d]
  f32x16 o[2] = {};
  __builtin_amdgcn_s_setprio(1);
#pragma unroll
  for (int dt = 0; dt < 2; ++dt) {
    const char* vr = (const char*)Vn + (dt * 32 + l31) * 512;
#pragma unroll
    for (int kt2 = 0; kt2 < 16; ++kt2) {
      bf16x8 vf = *(const bf16x8*)(vr + ((kt2 * 32 + hi * 16) ^ swz));
      o[dt] = __builtin_amdgcn_mfma_f32_32x32x16_bf16(pf[kt2], vf, o[dt], 0, 0, 0);
    }
  }
  __builtin_amdgcn_s_setprio(0);

  // epilogue: lane(hi, d=dt*32+l31) holds O^T[i = q*8 + hi*4 + m][d], reg 4q+m
  if (!IS_COL) {
#pragma unroll
    for (int dt = 0; dt < 2; ++dt) {
      int c = h * 64 + dt * 32 + l31;
      const float* xb = x + (size_t)c * NPIX + pixbase + i0w;
      unsigned short* ob = outnat + (size_t)c * NPIX + pixbase + i0w;
#pragma unroll
      for (int q = 0; q < 4; ++q) {
        int ib = q * 8 + hi * 4;
        float4 xv = *(const float4*)(xb + ib);
        float4 vv;
        vv.x = o[dt][q * 4 + 0] + xv.x;
        vv.y = o[dt][q * 4 + 1] + xv.y;
        vv.z = o[dt][q * 4 + 2] + xv.z;
        vv.w = o[dt][q * 4 + 3] + xv.w;
        ushort4 pk;
        pk.x = f2bf(vv.x); pk.y = f2bf(vv.y); pk.z = f2bf(vv.z); pk.w = f2bf(vv.w);
        *(ushort4*)(ob + ib) = pk;
        o[dt][q * 4 + 0] = vv.x; o[dt][q * 4 + 1] = vv.y;
        o[dt][q * 4 + 2] = vv.z; o[dt][q * 4 + 3] = vv.w;
      }
    }
    __syncthreads();                       // qkv reads done -> overlay Obt
    unsigned short* Obt = smem;            // [256 i][72 d]
#pragma unroll
    for (int dt = 0; dt < 2; ++dt) {
      int d = dt * 32 + l31;
#pragma unroll
      for (int q = 0; q < 4; ++q)
#pragma unroll
        for (int m = 0; m < 4; ++m)
          Obt[(i0w + q * 8 + hi * 4 + m) * 72 + d] = f2bf(o[dt][q * 4 + m]);
    }
    __syncthreads();
    int row = tid >> 1, half = tid & 1;
    const unsigned short* src = Obt + row * 72 + half * 32;
    unsigned short* dst = outbt + ((size_t)row * 256 + fix) * 512 + h * 64 + half * 32;
#pragma unroll
    for (int c4 = 0; c4 < 4; ++c4)
      *(uint4*)(dst + c4 * 8) = *(const uint4*)(src + c4 * 8);
  } else {
#pragma unroll
    for (int dt = 0; dt < 2; ++dt) {
      int c = h * 64 + dt * 32 + l31;
      unsigned short* ob = outnat + (size_t)c * NPIX + pixbase + i0w;
#pragma unroll
      for (int q = 0; q < 4; ++q) {
        ushort4 pkv;
        pkv.x = f2bf(o[dt][q * 4 + 0]);
        pkv.y = f2bf(o[dt][q * 4 + 1]);
        pkv.z = f2bf(o[dt][q * 4 + 2]);
        pkv.w = f2bf(o[dt][q * 4 + 3]);
        *(ushort4*)(ob + q * 8 + hi * 4) = pkv;
      }
    }
  }
}

// --------- final: out[c][s][l] = bf2f(out1nat) + colout_bt[c][l][s] ---------
__global__ __launch_bounds__(256) void k_final(const unsigned short* __restrict__ colt,
                                               const unsigned short* __restrict__ out1nat,
                                               float* __restrict__ out) {
  __shared__ unsigned short Xs[64 * 68];
  int c = blockIdx.y;
  int lt = blockIdx.x & 3, st = blockIdx.x >> 2;
  int l0 = lt * 64, s0 = st * 64;
  int t = threadIdx.x;
  for (int rep = 0; rep < 4; ++rep) {
    int f = rep * 256 + t, li = f >> 4, jj = f & 15;
    ushort4 v = *(const ushort4*)(colt + (size_t)c * NPIX + (size_t)(l0 + li) * 256 + s0 + jj * 4);
    *(ushort4*)(Xs + li * 68 + jj * 4) = v;
  }
  __syncthreads();
  int si = t >> 2, q = t & 3;
  size_t rowoff = (size_t)c * NPIX + (size_t)(s0 + si) * 256 + l0 + q * 16;
  float* drow = out + rowoff;
  for (int h4 = 0; h4 < 4; ++h4) {
    ushort4 nv = *(const ushort4*)(out1nat + rowoff + h4 * 4);
    float4 a;
    a.x = bf2f(nv.x) + bf2f(Xs[(q * 16 + h4 * 4 + 0) * 68 + si]);
    a.y = bf2f(nv.y) + bf2f(Xs[(q * 16 + h4 * 4 + 1) * 68 + si]);
    a.z = bf2f(nv.z) + bf2f(Xs[(q * 16 + h4 * 4 + 2) * 68 + si]);
    a.w = bf2f(nv.w) + bf2f(Xs[(q * 16 + h4 * 4 + 3) * 68 + si]);
    *(float4*)(drow + h4 * 4) = a;
  }
}

extern "C" void kernel_launch(void* const* d_in, const int* in_sizes, int n_in,
                              void* d_out, int out_size, void* d_ws, size_t ws_size,
                              hipStream_t stream) {
  const float* x  = (const float*)d_in[0];
  const float* Wr = (const float*)d_in[1];
  const float* br = (const float*)d_in[2];
  const float* Wc = (const float*)d_in[3];
  const float* bc = (const float*)d_in[4];
  float* out = (float*)d_out;
  char* ws = (char*)d_ws;
  unsigned short* xT     = (unsigned short*)(ws);                        // 64 MB [p][c]
  unsigned short* o1bt   = (unsigned short*)(ws + 67108864);             // 64 MB [l*256+s][c]
  unsigned short* colout = (unsigned short*)(ws + 134217728);            // 64 MB [c][l*256+s]
  unsigned short* o1nat  = (unsigned short*)(ws + 201326592);            // 64 MB [c][s*256+l]
  unsigned short* Wrb    = (unsigned short*)(ws + 268435456);            // 1.5 MB
  unsigned short* Wcb    = (unsigned short*)(ws + 270008320);            // 1.5 MB

  k_cvt<<<768, 256, 0, stream>>>(Wr, Wrb, 196608);
  k_cvt<<<768, 256, 0, stream>>>(Wc, Wcb, 196608);
  k_cvt_transpose<<<dim3(1024, 8), 256, 0, stream>>>(x, xT);
  // row side: fix = s, queries i = l; out1 = x + rowO
  k_fused<0><<<dim3(8, 256), 512, 0, stream>>>(xT, Wrb, br, x, o1nat, o1bt);
  // col side: fix = l, queries i = s; panel = out1^T (pixel order l*256+s)
  k_fused<1><<<dim3(8, 256), 512, 0, stream>>>(o1bt, Wcb, bc, nullptr, colout, nullptr);
  k_final<<<dim3(16, 512), 256, 0, stream>>>(colout, o1nat, out);
}